// Round 5
// baseline (238.343 us; speedup 1.0000x reference)
//
#include <hip/hip_runtime.h>
#include <hip/hip_bf16.h>
#include <stdint.h>

// Problem constants: B=4, N=4096, C=512, H=8, M=64, HD=64
#define QSZe 8388608ull  // elements per Q/K/V tensor (B*H*N*HD)

typedef __attribute__((ext_vector_type(8))) short bf16x8;
typedef __attribute__((ext_vector_type(4))) float f32x4;
typedef const __attribute__((address_space(1))) unsigned int* gas1_t;
typedef __attribute__((address_space(3))) unsigned int* las3_t;

__device__ __forceinline__ float bf2f(unsigned short u) {
  return __uint_as_float(((unsigned int)u) << 16);
}
__device__ __forceinline__ unsigned short f2bf(float f) {
  unsigned int u = __float_as_uint(f);
  unsigned int r = (u + 0x7FFFu + ((u >> 16) & 1u)) >> 16;
  return (unsigned short)r;
}
__device__ __forceinline__ void gload_lds16(const void* g, void* l) {
  __builtin_amdgcn_global_load_lds((gas1_t)g, (las3_t)l, 16, 0, 0);
}
// Per-wave fp32-input detection (same 256 half-words / predicate as before).
// Wave-uniform result, no barrier needed.
__device__ __forceinline__ unsigned int detect_f32(
    const unsigned short* __restrict__ raw_x) {
  int lane = threadIdx.x & 63;
  int big = 0;
#pragma unroll
  for (int i = 0; i < 4; i++) {
    int e = (raw_x[lane * 4 + i] >> 7) & 0xFF;
    big |= (e >= 0x8F) ? 1 : 0;
  }
  return (__ballot(big) != 0ull) ? 1u : 0u;
}

// ---------------------------------------------------------------------------
// Canonicalize ONLY the weights (qkv_w, proj_w) to bf16; x is now consumed
// raw by qkv_gemm (dtype branch there).  Zeroes gstat.  Grid 512 x 256.
// ---------------------------------------------------------------------------
__global__ __launch_bounds__(256) void conv_w(
    const void* __restrict__ rwq, const void* __restrict__ rwp,
    unsigned short* __restrict__ cwq, unsigned short* __restrict__ cwp,
    unsigned int* __restrict__ gstat, const unsigned short* __restrict__ rx) {
  int gid = blockIdx.x * 256 + threadIdx.x;
  if (gid == 0) {  // init atomicMax targets for the k2 phase
    gstat[0] = 0u;
    gstat[1] = 0u;
  }
  unsigned int f = detect_f32(rx);
  const void* src;
  unsigned short* dst;
  int i8;
  if (gid < 98304) {  // qkv_w: 3*512*512/8
    src = rwq; dst = cwq; i8 = gid * 8;
  } else {  // proj_w: 512*512/8
    src = rwp; dst = cwp; i8 = (gid - 98304) * 8;
  }
  if (f) {
    const float* fp = (const float*)src;
    float4 a = *(const float4*)(fp + i8);
    float4 b = *(const float4*)(fp + i8 + 4);
    unsigned short o[8] = {f2bf(a.x), f2bf(a.y), f2bf(a.z), f2bf(a.w),
                           f2bf(b.x), f2bf(b.y), f2bf(b.z), f2bf(b.w)};
    *(uint4*)(dst + i8) = *(const uint4*)o;
  } else {
    *(uint4*)(dst + i8) = *(const uint4*)((const unsigned short*)src + i8);
  }
}

// ---------------------------------------------------------------------------
// bf16 MFMA 64x64x64 helper for ns_kernel.  NO internal barrier (caller
// places one after each call; aliasing is safe per r4 analysis).
// ---------------------------------------------------------------------------
__device__ __forceinline__ void mmB(const unsigned short* A_R,
                                    const unsigned short* B_T,
                                    unsigned short* out_R,
                                    unsigned short* out_T, int wave, int lane,
                                    float s, float dg, float a7,
                                    const unsigned short* Aelt) {
  const int fr = lane & 15, fq = lane >> 4;
  bf16x8 af0 = *(const bf16x8*)&A_R[(wave * 16 + fr) * 64 + fq * 8];
  bf16x8 af1 = *(const bf16x8*)&A_R[(wave * 16 + fr) * 64 + 32 + fq * 8];
  f32x4 acc[4] = {};
#pragma unroll
  for (int j = 0; j < 4; j++) {
    bf16x8 b0 = *(const bf16x8*)&B_T[(j * 16 + fr) * 64 + fq * 8];
    bf16x8 b1 = *(const bf16x8*)&B_T[(j * 16 + fr) * 64 + 32 + fq * 8];
    acc[j] = __builtin_amdgcn_mfma_f32_16x16x32_bf16(af0, b0, acc[j], 0, 0, 0);
    acc[j] = __builtin_amdgcn_mfma_f32_16x16x32_bf16(af1, b1, acc[j], 0, 0, 0);
  }
  float ael[4][4];
  if (Aelt) {
#pragma unroll
    for (int j = 0; j < 4; j++)
#pragma unroll
      for (int r = 0; r < 4; r++)
        ael[j][r] = bf2f(Aelt[(wave * 16 + fq * 4 + r) * 64 + j * 16 + fr]);
  }
#pragma unroll
  for (int j = 0; j < 4; j++) {
    int col = j * 16 + fr;
    unsigned short pack[4];
#pragma unroll
    for (int r = 0; r < 4; r++) {
      int row = wave * 16 + fq * 4 + r;
      float v = s * acc[j][r] + ((row == col) ? dg : 0.0f);
      if (Aelt) v += a7 * ael[j][r];
      unsigned short bv = f2bf(v);
      if (out_R) out_R[row * 64 + col] = bv;
      pack[r] = bv;
    }
    if (out_T)
      *(uint2*)&out_T[col * 64 + wave * 16 + fq * 4] = *(const uint2*)pack;
  }
}

// ---------------------------------------------------------------------------
// Kernel A (MFMA, C^T orientation): qkv = x @ qkv_w^T via D = W @ X^T.
// 128f x 256t tile, 8 waves, wave 64x64 (acc[4][4]).  B staged DIRECTLY from
// raw x: bf16 inputs -> gload_lds with pre-swizzled source; fp32 inputs ->
// reg-load + f2bf + ds_write_b128 to write-side-swizzled slot (z^srow) —
// both produce the SAME swizzled LDS layout (rule #21).  T2 read swizzle +
// T1 XCD chunk swizzle (nwg=768=8*96).  Pooling fused in epilogue.
// Grid (12, 64), 512 thr, 48 KB LDS.
// ---------------------------------------------------------------------------
__global__ __launch_bounds__(512) void qkv_gemm_mfma(
    const unsigned short* __restrict__ w, const void* __restrict__ xraw,
    unsigned short* __restrict__ qkv, float* __restrict__ Ql,
    float* __restrict__ Kl, unsigned short* __restrict__ Qlb,
    unsigned short* __restrict__ Klb) {
  __shared__ __align__(16) unsigned short At[128 * 64];  // 16 KB (features)
  __shared__ __align__(16) unsigned short Bt[256 * 64];  // 32 KB (tokens)
  const int t = threadIdx.x;
  const int lane = t & 63, wave = t >> 6;  // wave 0..7
  const int wf = wave >> 2, wt = wave & 3; // 2 feature-halves x 4 token-quads
  const unsigned int isf = detect_f32((const unsigned short*)xraw);
  // T1: bijective chunk swizzle, nwg = 768 = 8 * 96
  const int lin = blockIdx.x + blockIdx.y * 12;
  const int swz = (lin & 7) * 96 + (lin >> 3);
  const int f0 = (swz % 12) * 128, n0g = (swz / 12) * 256;
  const int srow = lane >> 3, z = lane & 7;
  const int skc = (z ^ srow) * 8;  // swizzled source chunk (bf16/gload path)
  const int fr = lane & 15, fq = lane >> 4;
  const int rsw = fr & 7;  // read-side swizzle key (row & 7)
  f32x4 acc[4][4] = {};

  for (int k0 = 0; k0 < 512; k0 += 64) {
#pragma unroll
    for (int s = 0; s < 2; s++) {  // At: 16 instr total, 2 per wave
      int inst = wave * 2 + s;
      int row = inst * 8 + srow;
      gload_lds16(w + (size_t)(f0 + row) * 512 + k0 + skc, &At[inst * 512]);
    }
    if (!isf) {  // bf16 input: x raw IS the canonical bf16 layout
      const unsigned short* xb = (const unsigned short*)xraw;
#pragma unroll
      for (int s = 0; s < 4; s++) {  // Bt: 32 instr total, 4 per wave
        int inst = wave * 4 + s;
        int row = inst * 8 + srow;
        gload_lds16(xb + (size_t)(n0g + row) * 512 + k0 + skc,
                    &Bt[inst * 512]);
      }
    } else {  // fp32 input: reg-stage + convert + write-side swizzle
      const float* xf = (const float*)xraw;
#pragma unroll
      for (int s = 0; s < 4; s++) {
        int row = (wave * 4 + s) * 8 + srow;
        const float* src = xf + (size_t)(n0g + row) * 512 + k0 + z * 8;
        float4 a = *(const float4*)src;
        float4 b = *(const float4*)(src + 4);
        unsigned short o[8] = {f2bf(a.x), f2bf(a.y), f2bf(a.z), f2bf(a.w),
                               f2bf(b.x), f2bf(b.y), f2bf(b.z), f2bf(b.w)};
        *(uint4*)&Bt[row * 64 + skc] = *(const uint4*)o;  // slot z^srow
      }
    }
    __syncthreads();
#pragma unroll
    for (int kk = 0; kk < 64; kk += 32) {
      const int swo = (((kk >> 3) + fq) ^ rsw) << 3;
      bf16x8 af[4], bxf[4];
#pragma unroll
      for (int i = 0; i < 4; i++)
        af[i] = *(const bf16x8*)&At[(wf * 64 + i * 16 + fr) * 64 + swo];
#pragma unroll
      for (int j = 0; j < 4; j++)
        bxf[j] = *(const bf16x8*)&Bt[(wt * 64 + j * 16 + fr) * 64 + swo];
#pragma unroll
      for (int i = 0; i < 4; i++)
#pragma unroll
        for (int j = 0; j < 4; j++)
          acc[i][j] = __builtin_amdgcn_mfma_f32_16x16x32_bf16(
              af[i], bxf[j], acc[i][j], 0, 0, 0);
    }
    __syncthreads();
  }
  // epilogue: wave-uniform (which, h); rows = features, cols = tokens
  const int fbase = f0 + wf * 64;
  const int which = fbase >> 9;
  const int h = (fbase >> 6) & 7;
  const float scale = (which < 2) ? 0.3535533905932738f : 1.0f;
  const int b_ = n0g >> 12;
  const int bh = b_ * 8 + h;
  const int m_loc = ((n0g + wt * 64) & 4095) >> 6;  // landmark (wave-uniform)
#pragma unroll
  for (int i = 0; i < 4; i++) {
    int d0 = i * 16 + fq * 4;
#pragma unroll
    for (int j = 0; j < 4; j++) {
      int nn = (n0g + wt * 64 + j * 16 + fr) & 4095;
      unsigned short pack[4];
#pragma unroll
      for (int r = 0; r < 4; r++) pack[r] = f2bf(acc[i][j][r] * scale);
      *(uint2*)&qkv[(size_t)which * QSZe + ((size_t)bh * 4096 + nn) * 64 +
                    d0] = *(const uint2*)pack;
    }
  }
  if (which < 2) {  // fused landmark pooling (mean over this wave's 64 tokens)
    const float ps = scale * (1.0f / 64.0f);
#pragma unroll
    for (int i = 0; i < 4; i++) {
      float sm[4];
#pragma unroll
      for (int r = 0; r < 4; r++)
        sm[r] = acc[i][0][r] + acc[i][1][r] + acc[i][2][r] + acc[i][3][r];
#pragma unroll
      for (int mask = 1; mask < 16; mask <<= 1)
#pragma unroll
        for (int r = 0; r < 4; r++) sm[r] += __shfl_xor(sm[r], mask, 64);
      if (fr == 0) {
        int d0 = i * 16 + fq * 4;
        float4 v4 = make_float4(sm[0] * ps, sm[1] * ps, sm[2] * ps, sm[3] * ps);
        unsigned short pk[4] = {f2bf(v4.x), f2bf(v4.y), f2bf(v4.z), f2bf(v4.w)};
        size_t off = (size_t)bh * 4096 + m_loc * 64 + d0;
        if (which == 0) {
          *(float4*)&Ql[off] = v4;
          *(uint2*)&Qlb[off] = *(const uint2*)pk;
        } else {
          *(float4*)&Kl[off] = v4;
          *(uint2*)&Klb[off] = *(const uint2*)pk;
        }
      }
    }
  }
}

// ---------------------------------------------------------------------------
// Kernel E+C fused: slab<8 -> kernel_3 + P@V partials (k3 body);
// slab==8 -> kernel_2 softmax + global colsum/rowsum max (k2 body).
// k2 and k3 are independent (both depend only on qkv_gemm outputs), so the
// fused grid overlaps them and removes one dispatch boundary.
// Grid (9 , 32 bh), 256 thr.  LDS aliased in one 35840 B buffer.
// ---------------------------------------------------------------------------
__global__ __launch_bounds__(256) void k3k2_mfma(
    const unsigned short* __restrict__ Qlb,
    const unsigned short* __restrict__ qkv, float* __restrict__ Wp,
    float* __restrict__ sp, const float* __restrict__ Ql,
    const float* __restrict__ Kl, float* __restrict__ k2,
    unsigned int* __restrict__ gstat) {
  __shared__ __align__(16) unsigned char SM[35840];
  const int t = threadIdx.x;
  const int lane = t & 63, wave = t >> 6;
  const int slab = blockIdx.x, bh = blockIdx.y;

  if (slab == 8) {  // ------------------ k2 body ------------------
    float* KlT = (float*)SM;           // [d][l] 16384 B
    float* Ps = (float*)(SM + 16384);  // [64][65] 16640 B
#pragma unroll
    for (int i = 0; i < 16; i++) {
      int idx = i * 256 + t;
      KlT[(idx & 63) * 64 + (idx >> 6)] = Kl[bh * 4096 + idx];
    }
    __syncthreads();
    for (int r = wave * 16; r < wave * 16 + 16; r++) {
      float qv = Ql[(bh * 64 + r) * 64 + lane];
      float acc = 0.f;
#pragma unroll
      for (int k = 0; k < 64; k++)
        acc += __shfl(qv, k, 64) * KlT[k * 64 + lane];
      float mx = acc;
#pragma unroll
      for (int o = 32; o > 0; o >>= 1) mx = fmaxf(mx, __shfl_xor(mx, o, 64));
      float e = __expf(acc - mx);
      float s = e;
#pragma unroll
      for (int o = 32; o > 0; o >>= 1) s += __shfl_xor(s, o, 64);
      float p = e / s;
      k2[(bh * 64 + r) * 64 + lane] = p;
      Ps[r * 65 + lane] = p;
    }
    __syncthreads();
    float val = 0.f;
    if (t < 64) {
      for (int r = 0; r < 64; r++) val += Ps[r * 65 + t];  // column sums
    } else if (t < 128) {
      int r = t - 64;
      for (int c = 0; c < 64; c++) val += Ps[r * 65 + c];  // row sums
    }
    float mv = val;
#pragma unroll
    for (int o = 32; o > 0; o >>= 1) mv = fmaxf(mv, __shfl_xor(mv, o, 64));
    if (t == 0) atomicMax(gstat + 0, __float_as_uint(mv));
    if (t == 64) atomicMax(gstat + 1, __float_as_uint(mv));
    return;
  }
  // ------------------ k3 body ------------------
  unsigned short* Et = (unsigned short*)SM;            // [m][n] 17408 B
  unsigned short* Vt = (unsigned short*)(SM + 17408);  // [d][n] 17408 B
  float* scol_l = (float*)(SM + 34816);                // [4][64] 1024 B
  const int fr = lane & 15, fq = lane >> 4;
  const int n_base = slab * 512;
  const unsigned short* Kb = qkv + QSZe + (size_t)bh * 262144;
  const unsigned short* Vb = qkv + 2 * QSZe + (size_t)bh * 262144;
  const unsigned short* Qlp = Qlb + bh * 4096;

  bf16x8 qb[2][4];
#pragma unroll
  for (int h = 0; h < 2; h++)
#pragma unroll
    for (int j = 0; j < 4; j++)
      qb[h][j] = *(const bf16x8*)(Qlp + (j * 16 + fr) * 64 + h * 32 + fq * 8);

  f32x4 accW[4] = {};
  float scol[4] = {0.f, 0.f, 0.f, 0.f};

  for (int sc = 0; sc < 4; sc++) {
    const int n0 = n_base + sc * 128;
    {
      int n = t & 127, dg = t >> 7;
#pragma unroll
      for (int i = 0; i < 4; i++) {
        int d0 = (dg + 2 * i) * 8;
        uint4 v = *(const uint4*)(Vb + (size_t)(n0 + n) * 64 + d0);
        const unsigned short* s = (const unsigned short*)&v;
#pragma unroll
        for (int u = 0; u < 8; u++) Vt[(d0 + u) * 136 + n] = s[u];
      }
    }
    f32x4 acc[2][4] = {};
#pragma unroll
    for (int i = 0; i < 2; i++) {
      const unsigned short* Kr =
          Kb + (size_t)(n0 + wave * 32 + i * 16 + fr) * 64;
      bf16x8 a0 = *(const bf16x8*)(Kr + fq * 8);
      bf16x8 a1 = *(const bf16x8*)(Kr + 32 + fq * 8);
#pragma unroll
      for (int j = 0; j < 4; j++) {
        acc[i][j] = __builtin_amdgcn_mfma_f32_16x16x32_bf16(a0, qb[0][j],
                                                            acc[i][j], 0, 0, 0);
        acc[i][j] = __builtin_amdgcn_mfma_f32_16x16x32_bf16(a1, qb[1][j],
                                                            acc[i][j], 0, 0, 0);
      }
    }
#pragma unroll
    for (int i = 0; i < 2; i++)
#pragma unroll
      for (int j = 0; j < 4; j++) {
        unsigned short pack[4];
        float s4 = 0.f;
#pragma unroll
        for (int r = 0; r < 4; r++) {
          float e = __expf(acc[i][j][r]);
          s4 += e;
          pack[r] = f2bf(e);
        }
        scol[j] += s4;
        *(uint2*)&Et[(j * 16 + fr) * 136 + wave * 32 + i * 16 + fq * 4] =
            *(const uint2*)pack;
      }
    __syncthreads();
#pragma unroll
    for (int kk = 0; kk < 128; kk += 32) {
      bf16x8 ap = *(const bf16x8*)&Et[(wave * 16 + fr) * 136 + kk + fq * 8];
#pragma unroll
      for (int j = 0; j < 4; j++) {
        bf16x8 bv = *(const bf16x8*)&Vt[(j * 16 + fr) * 136 + kk + fq * 8];
        accW[j] =
            __builtin_amdgcn_mfma_f32_16x16x32_bf16(ap, bv, accW[j], 0, 0, 0);
      }
    }
    __syncthreads();
  }
#pragma unroll
  for (int j = 0; j < 4; j++) {
    float s = scol[j];
    s += __shfl_xor(s, 16, 64);
    s += __shfl_xor(s, 32, 64);
    if (fq == 0) scol_l[wave * 64 + j * 16 + fr] = s;
  }
  __syncthreads();
  if (t < 64)
    sp[(bh * 8 + slab) * 64 + t] = scol_l[0 * 64 + t] + scol_l[1 * 64 + t] +
                                   scol_l[2 * 64 + t] + scol_l[3 * 64 + t];
  float* wpo = Wp + ((size_t)bh * 8 + slab) * 4096;
#pragma unroll
  for (int j = 0; j < 4; j++)
#pragma unroll
    for (int r = 0; r < 4; r++)
      wpo[(wave * 16 + fq * 4 + r) * 64 + j * 16 + fr] = accW[j][r];
}

// ---------------------------------------------------------------------------
// Kernel D (MFMA): Newton-Schulz (6 iters) + FUSED k3 reduction (W from
// Wp/sp) + Z^T -> Ztb[bh][d][m] bf16.  One block per (b,h).
// One barrier per mmB.
// ---------------------------------------------------------------------------
__global__ __launch_bounds__(256) void ns_kernel(
    const float* __restrict__ k2g, const unsigned int* __restrict__ gstat,
    const float* __restrict__ Wp, const float* __restrict__ sp,
    unsigned short* __restrict__ Ztb) {
  __shared__ __align__(16) unsigned short L[8 * 4096];
  __shared__ float ssum[64];
  unsigned short* K2R = L;
  unsigned short* VR = L + 4096;
  unsigned short* VT = L + 2 * 4096;
  unsigned short* AR = L + 3 * 4096;
  unsigned short* AT = L + 4 * 4096;
  unsigned short* T2T = L + 5 * 4096;
  unsigned short* T3T = L + 6 * 4096;
  unsigned short* WT = L + 7 * 4096;
  const int t = threadIdx.x, bh = blockIdx.x;
  const int lane = t & 63, wave = t >> 6;
  const float scale =
      1.0f / (__uint_as_float(gstat[0]) * __uint_as_float(gstat[1]));
  const float* k2p = k2g + bh * 4096;
  if (t < 64) {
    float s = 0.f;
#pragma unroll
    for (int c = 0; c < 8; c++) s += sp[(bh * 8 + c) * 64 + t];
    ssum[t] = s;
  }
  __syncthreads();
#pragma unroll
  for (int i = 0; i < 16; i++) {
    int idx = i * 256 + t;
    int m = idx >> 6, d = idx & 63;
    float kv = k2p[idx];
    K2R[idx] = f2bf(kv);
    VT[idx] = f2bf(kv * scale);
    VR[idx] = f2bf(k2p[d * 64 + m] * scale);
    float wv = 0.f;
#pragma unroll
    for (int cc = 0; cc < 8; cc++)
      wv += Wp[((size_t)(bh * 8 + cc)) * 4096 + idx];
    WT[d * 64 + m] = f2bf(wv / ssum[m]);
  }
  __syncthreads();
  for (int it = 0; it < 6; it++) {
    mmB(K2R, VT, AR, AT, wave, lane, 1.0f, 0.0f, 0.0f, nullptr);
    __syncthreads();
    mmB(AR, AT, nullptr, T2T, wave, lane, 1.0f, 15.0f, -7.0f, AR);
    __syncthreads();
    mmB(AR, T2T, nullptr, T3T, wave, lane, -1.0f, 13.0f, 0.0f, nullptr);
    __syncthreads();
    mmB(VR, T3T, VR, VT, wave, lane, 0.25f, 0.0f, 0.0f, nullptr);
    __syncthreads();
  }
  {
    const int fr = lane & 15, fq = lane >> 4;
    bf16x8 af0 = *(const bf16x8*)&WT[(wave * 16 + fr) * 64 + fq * 8];
    bf16x8 af1 = *(const bf16x8*)&WT[(wave * 16 + fr) * 64 + 32 + fq * 8];
    f32x4 acc[4] = {};
#pragma unroll
    for (int j = 0; j < 4; j++) {
      bf16x8 b0 = *(const bf16x8*)&VR[(j * 16 + fr) * 64 + fq * 8];
      bf16x8 b1 = *(const bf16x8*)&VR[(j * 16 + fr) * 64 + 32 + fq * 8];
      acc[j] =
          __builtin_amdgcn_mfma_f32_16x16x32_bf16(af0, b0, acc[j], 0, 0, 0);
      acc[j] =
          __builtin_amdgcn_mfma_f32_16x16x32_bf16(af1, b1, acc[j], 0, 0, 0);
    }
#pragma unroll
    for (int j = 0; j < 4; j++) {
      int m = j * 16 + fr;
#pragma unroll
      for (int r = 0; r < 4; r++) {
        int d = wave * 16 + fq * 4 + r;
        Ztb[bh * 4096 + d * 64 + m] = f2bf(acc[j][r]);
      }
    }
  }
}

// ---------------------------------------------------------------------------
// Kernel G (MFMA): kernel_1 softmax fused with X = P @ Z. Grid (32, 32).
// Qt tile XOR-swizzled (Ps already 72-padded: conflict-free).
// ---------------------------------------------------------------------------
__global__ __launch_bounds__(256) void k1x_mfma(
    const unsigned short* __restrict__ qkv,
    const unsigned short* __restrict__ Klb,
    const unsigned short* __restrict__ Ztb, unsigned short* __restrict__ X) {
  __shared__ __align__(16) unsigned short Qt[128 * 64];  // 16 KB
  __shared__ __align__(16) unsigned short Ps[128 * 72];  // 18 KB
  const int t = threadIdx.x;
  const int lane = t & 63, wave = t >> 6;
  const int fr = lane & 15, fq = lane >> 4;
  const int rsw = fr & 7;
  const int bh = blockIdx.x;
  const int n0 = blockIdx.y * 128;
  const unsigned short* Qb = qkv + (size_t)bh * 262144 + (size_t)n0 * 64;
  const unsigned short* Klp = Klb + bh * 4096;
  const unsigned short* Ztp = Ztb + bh * 4096;

  {
    const int srow = lane >> 3, skc = ((lane & 7) ^ srow) * 8;  // swizzled src
#pragma unroll
    for (int s = 0; s < 4; s++) {
      int inst = wave * 4 + s;
      gload_lds16(Qb + (size_t)(inst * 8 + srow) * 64 + skc, &Qt[inst * 512]);
    }
  }
  __syncthreads();

  f32x4 acc[2][4] = {};
#pragma unroll
  for (int kk = 0; kk < 64; kk += 32) {
    bf16x8 af[2], bg[4];
#pragma unroll
    for (int i = 0; i < 2; i++)
      af[i] = *(const bf16x8*)&Qt[(wave * 32 + i * 16 + fr) * 64 +
                                  ((((kk >> 3) + fq) ^ rsw) << 3)];
#pragma unroll
    for (int j = 0; j < 4; j++)
      bg[j] = *(const bf16x8*)(Klp + (j * 16 + fr) * 64 + kk + fq * 8);
#pragma unroll
    for (int i = 0; i < 2; i++)
#pragma unroll
      for (int j = 0; j < 4; j++)
        acc[i][j] = __builtin_amdgcn_mfma_f32_16x16x32_bf16(af[i], bg[j],
                                                            acc[i][j], 0, 0, 0);
  }

#pragma unroll
  for (int i = 0; i < 2; i++) {
    float sr[4] = {0.f, 0.f, 0.f, 0.f};
#pragma unroll
    for (int j = 0; j < 4; j++)
#pragma unroll
      for (int r = 0; r < 4; r++) {
        float e = __expf(acc[i][j][r]);
        acc[i][j][r] = e;
        sr[r] += e;
      }
#pragma unroll
    for (int mask = 1; mask < 16; mask <<= 1)
#pragma unroll
      for (int r = 0; r < 4; r++) sr[r] += __shfl_xor(sr[r], mask, 64);
    float is[4];
#pragma unroll
    for (int r = 0; r < 4; r++) is[r] = 1.0f / sr[r];
#pragma unroll
    for (int j = 0; j < 4; j++)
#pragma unroll
      for (int r = 0; r < 4; r++)
        Ps[(wave * 32 + i * 16 + fq * 4 + r) * 72 + j * 16 + fr] =
            f2bf(acc[i][j][r] * is[r]);
  }
  __syncthreads();

  f32x4 ax[2][4] = {};
#pragma unroll
  for (int kk = 0; kk < 64; kk += 32) {
    bf16x8 ap[2], bz[4];
#pragma unroll
    for (int i = 0; i < 2; i++)
      ap[i] =
          *(const bf16x8*)&Ps[(wave * 32 + i * 16 + fr) * 72 + kk + fq * 8];
#pragma unroll
    for (int j = 0; j < 4; j++)
      bz[j] = *(const bf16x8*)(Ztp + (j * 16 + fr) * 64 + kk + fq * 8);
#pragma unroll
    for (int i = 0; i < 2; i++)
#pragma unroll
      for (int j = 0; j < 4; j++)
        ax[i][j] = __builtin_amdgcn_mfma_f32_16x16x32_bf16(ap[i], bz[j],
                                                           ax[i][j], 0, 0, 0);
  }

  const int b_ = bh >> 3, h = bh & 7;
#pragma unroll
  for (int i = 0; i < 2; i++) {
#pragma unroll
    for (int j = 0; j < 4; j++) {
      int c = h * 64 + j * 16 + fr;
#pragma unroll
      for (int r = 0; r < 4; r++) {
        int n = n0 + wave * 32 + i * 16 + fq * 4 + r;
        X[((size_t)(b_ * 4096 + n)) * 512 + c] = f2bf(ax[i][j][r]);
      }
    }
  }
}

// ---------------------------------------------------------------------------
// Kernel H (MFMA): out = X @ proj_w^T + proj_b, fp32 OUT. Grid (4, 128).
// Round-1 block mapping (no T1), T2 swizzle, single buffer.
// Bias converted inline (self-detect dtype).
// ---------------------------------------------------------------------------
__global__ __launch_bounds__(256) void proj_gemm_mfma(
    const unsigned short* __restrict__ X, const unsigned short* __restrict__ w,
    const unsigned short* __restrict__ raw_x, const void* __restrict__ raw_b,
    float* __restrict__ out) {
  __shared__ __align__(16) unsigned short At[128 * 64];
  __shared__ __align__(16) unsigned short Bt[128 * 64];
  const int t = threadIdx.x;
  const unsigned int f = detect_f32(raw_x);
  const int lane = t & 63, wave = t >> 6;
  const int wr = wave >> 1, wc = wave & 1;
  const int i0 = blockIdx.y * 128, j0 = blockIdx.x * 128;
  const int srow = lane >> 3;
  const int skc = ((lane & 7) ^ srow) * 8;  // swizzled src
  const int fr = lane & 15, fq = lane >> 4;
  const int rsw = fr & 7;
  f32x4 acc[4][4] = {};

  for (int k0 = 0; k0 < 512; k0 += 64) {
#pragma unroll
    for (int s = 0; s < 4; s++) {
      int inst = wave * 4 + s;
      int row = inst * 8 + srow;
      gload_lds16(X + (size_t)(i0 + row) * 512 + k0 + skc, &At[inst * 512]);
      gload_lds16(w + (size_t)(j0 + row) * 512 + k0 + skc, &Bt[inst * 512]);
    }
    __syncthreads();
#pragma unroll
    for (int kk = 0; kk < 64; kk += 32) {
      const int swo = (((kk >> 3) + fq) ^ rsw) << 3;
      bf16x8 af[4], bg[4];
#pragma unroll
      for (int i = 0; i < 4; i++)
        af[i] = *(const bf16x8*)&At[(wr * 64 + i * 16 + fr) * 64 + swo];
#pragma unroll
      for (int j = 0; j < 4; j++)
        bg[j] = *(const bf16x8*)&Bt[(wc * 64 + j * 16 + fr) * 64 + swo];
#pragma unroll
      for (int i = 0; i < 4; i++)
#pragma unroll
        for (int j = 0; j < 4; j++)
          acc[i][j] = __builtin_amdgcn_mfma_f32_16x16x32_bf16(
              af[i], bg[j], acc[i][j], 0, 0, 0);
    }
    __syncthreads();
  }
#pragma unroll
  for (int j = 0; j < 4; j++) {
    int col = j0 + wc * 64 + j * 16 + fr;  // 0..511
    float bia = f ? ((const float*)raw_b)[col]
                  : bf2f(((const unsigned short*)raw_b)[col]);
#pragma unroll
    for (int i = 0; i < 4; i++) {
      int rbase = i0 + wr * 64 + i * 16 + fq * 4;
#pragma unroll
      for (int r = 0; r < 4; r++) {
        out[(size_t)(rbase + r) * 512 + col] = acc[i][j][r] + bia;
      }
    }
  }
}

// ---------------------------------------------------------------------------
extern "C" void kernel_launch(void* const* d_in, const int* in_sizes, int n_in,
                              void* d_out, int out_size, void* d_ws,
                              size_t ws_size, hipStream_t stream) {
  (void)in_sizes; (void)n_in; (void)out_size; (void)ws_size;

  char* w8 = (char*)d_ws;
  unsigned short* cwq = (unsigned short*)(w8 + 16777216);  // qkv_w canon
  unsigned short* cwp = (unsigned short*)(w8 + 18350080);  // proj_w canon
  unsigned short* qkv = (unsigned short*)(w8 + 18876416);  // Q,K,V bf16
  unsigned short* X   = (unsigned short*)(w8 + 69208064);  // attn out bf16
  float* Ql = (float*)(w8 + 85985280);
  float* Kl = (float*)(w8 + 86509568);
  float* k2 = (float*)(w8 + 87033856);
  unsigned short* Ztb = (unsigned short*)(w8 + 88082432);  // Z^T bf16 [bh][d][m]
  unsigned int* gstat = (unsigned int*)(w8 + 88606720);  // [cmax, rmax]
  float* Wp = (float*)(w8 + 88608768);                   // 32*8*4096*4 B
  float* sp = (float*)(w8 + 92803072);                   // 32*8*64*4 B
  unsigned short* Klb = (unsigned short*)(w8 + 92868608); // Kl bf16
  unsigned short* Qlb = (unsigned short*)(w8 + 93130752); // Ql bf16

  conv_w<<<512, 256, 0, stream>>>(d_in[1], d_in[2], cwq, cwp, gstat,
                                  (const unsigned short*)d_in[0]);
  qkv_gemm_mfma<<<dim3(12, 64), 512, 0, stream>>>(cwq, d_in[0], qkv, Ql, Kl,
                                                  Qlb, Klb);
  k3k2_mfma<<<dim3(9, 32), 256, 0, stream>>>(Qlb, qkv, Wp, sp, Ql, Kl, k2,
                                             gstat);
  ns_kernel<<<32, 256, 0, stream>>>(k2, gstat, Wp, sp, Ztb);
  k1x_mfma<<<dim3(32, 32), 256, 0, stream>>>(qkv, Klb, Ztb, X);
  proj_gemm_mfma<<<dim3(4, 128), 256, 0, stream>>>(
      X, cwp, (const unsigned short*)d_in[0], d_in[3], (float*)d_out);
}

// Round 6
// 225.062 us; speedup vs baseline: 1.0590x; 1.0590x over previous
//
#include <hip/hip_runtime.h>
#include <hip/hip_bf16.h>
#include <stdint.h>

// Problem constants: B=4, N=4096, C=512, H=8, M=64, HD=64
#define QSZe 8388608ull  // elements per Q/K/V tensor (B*H*N*HD)

typedef __attribute__((ext_vector_type(8))) short bf16x8;
typedef __attribute__((ext_vector_type(4))) float f32x4;
typedef const __attribute__((address_space(1))) unsigned int* gas1_t;
typedef __attribute__((address_space(3))) unsigned int* las3_t;

__device__ __forceinline__ float bf2f(unsigned short u) {
  return __uint_as_float(((unsigned int)u) << 16);
}
__device__ __forceinline__ unsigned short f2bf(float f) {
  unsigned int u = __float_as_uint(f);
  unsigned int r = (u + 0x7FFFu + ((u >> 16) & 1u)) >> 16;
  return (unsigned short)r;
}
__device__ __forceinline__ void gload_lds16(const void* g, void* l) {
  __builtin_amdgcn_global_load_lds((gas1_t)g, (las3_t)l, 16, 0, 0);
}
// Per-wave fp32-input detection (same 256 half-words / predicate as the
// original detect_bias).  Wave-uniform result, no barrier needed.
__device__ __forceinline__ unsigned int detect_f32(
    const unsigned short* __restrict__ raw_x) {
  int lane = threadIdx.x & 63;
  int big = 0;
#pragma unroll
  for (int i = 0; i < 4; i++) {
    int e = (raw_x[lane * 4 + i] >> 7) & 0xFF;
    big |= (e >= 0x8F) ? 1 : 0;
  }
  return (__ballot(big) != 0ull) ? 1u : 0u;
}

// ---------------------------------------------------------------------------
// Canonicalize x (only if fp32), qkv_w, proj_w to bf16 in ONE dispatch.
// If input is bf16, the x-region blocks skip the copy entirely (qkv_gemm
// reads raw x directly via pointer select).  Zeroes gstat.  Grid 4608 x 256.
// ---------------------------------------------------------------------------
__global__ __launch_bounds__(256) void conv_all(
    const void* __restrict__ rx, const void* __restrict__ rwq,
    const void* __restrict__ rwp, unsigned short* __restrict__ cx,
    unsigned short* __restrict__ cwq, unsigned short* __restrict__ cwp,
    unsigned int* __restrict__ gstat) {
  int gid = blockIdx.x * 256 + threadIdx.x;
  if (gid == 0) {  // init atomicMax targets for the k2 phase
    gstat[0] = 0u;
    gstat[1] = 0u;
  }
  unsigned int f = detect_f32((const unsigned short*)rx);
  const void* src;
  unsigned short* dst;
  int i8;
  if (gid < 1048576) {
    if (!f) return;  // bf16 input: qkv reads raw x, no copy needed
    src = rx; dst = cx; i8 = gid * 8;
  } else if (gid < 1146880) {
    src = rwq; dst = cwq; i8 = (gid - 1048576) * 8;
  } else {
    src = rwp; dst = cwp; i8 = (gid - 1146880) * 8;
  }
  if (f) {
    const float* fp = (const float*)src;
    float4 a = *(const float4*)(fp + i8);
    float4 b = *(const float4*)(fp + i8 + 4);
    unsigned short o[8] = {f2bf(a.x), f2bf(a.y), f2bf(a.z), f2bf(a.w),
                           f2bf(b.x), f2bf(b.y), f2bf(b.z), f2bf(b.w)};
    *(uint4*)(dst + i8) = *(const uint4*)o;
  } else {
    *(uint4*)(dst + i8) = *(const uint4*)((const unsigned short*)src + i8);
  }
}

// ---------------------------------------------------------------------------
// bf16 MFMA 64x64x64 helper for ns_kernel.  NO internal barrier (caller
// places one after each call; aliasing is safe per r4 analysis).
// ---------------------------------------------------------------------------
__device__ __forceinline__ void mmB(const unsigned short* A_R,
                                    const unsigned short* B_T,
                                    unsigned short* out_R,
                                    unsigned short* out_T, int wave, int lane,
                                    float s, float dg, float a7,
                                    const unsigned short* Aelt) {
  const int fr = lane & 15, fq = lane >> 4;
  bf16x8 af0 = *(const bf16x8*)&A_R[(wave * 16 + fr) * 64 + fq * 8];
  bf16x8 af1 = *(const bf16x8*)&A_R[(wave * 16 + fr) * 64 + 32 + fq * 8];
  f32x4 acc[4] = {};
#pragma unroll
  for (int j = 0; j < 4; j++) {
    bf16x8 b0 = *(const bf16x8*)&B_T[(j * 16 + fr) * 64 + fq * 8];
    bf16x8 b1 = *(const bf16x8*)&B_T[(j * 16 + fr) * 64 + 32 + fq * 8];
    acc[j] = __builtin_amdgcn_mfma_f32_16x16x32_bf16(af0, b0, acc[j], 0, 0, 0);
    acc[j] = __builtin_amdgcn_mfma_f32_16x16x32_bf16(af1, b1, acc[j], 0, 0, 0);
  }
  float ael[4][4];
  if (Aelt) {
#pragma unroll
    for (int j = 0; j < 4; j++)
#pragma unroll
      for (int r = 0; r < 4; r++)
        ael[j][r] = bf2f(Aelt[(wave * 16 + fq * 4 + r) * 64 + j * 16 + fr]);
  }
#pragma unroll
  for (int j = 0; j < 4; j++) {
    int col = j * 16 + fr;
    unsigned short pack[4];
#pragma unroll
    for (int r = 0; r < 4; r++) {
      int row = wave * 16 + fq * 4 + r;
      float v = s * acc[j][r] + ((row == col) ? dg : 0.0f);
      if (Aelt) v += a7 * ael[j][r];
      unsigned short bv = f2bf(v);
      if (out_R) out_R[row * 64 + col] = bv;
      pack[r] = bv;
    }
    if (out_T)
      *(uint2*)&out_T[col * 64 + wave * 16 + fq * 4] = *(const uint2*)pack;
  }
}

// ---------------------------------------------------------------------------
// Kernel A (MFMA, C^T orientation): qkv = x @ qkv_w^T via D = W @ X^T.
// 128f x 256t tile, 8 waves, wave 64x64 (acc[4][4]).  B staged via gload_lds
// from xb = (fp32 input ? cx : raw x) — wave-uniform pointer select, single
// staging path (round-4 proven).  T2 XOR-swizzled LDS (both-sides rule #21)
// + T1 XCD chunk swizzle (nwg=768=8*96).  Pooling fused in epilogue.
// Grid (12, 64), 512 thr, 48 KB LDS.
// ---------------------------------------------------------------------------
__global__ __launch_bounds__(512) void qkv_gemm_mfma(
    const unsigned short* __restrict__ w, const void* __restrict__ xraw,
    const unsigned short* __restrict__ cx, unsigned short* __restrict__ qkv,
    float* __restrict__ Ql, float* __restrict__ Kl,
    unsigned short* __restrict__ Qlb, unsigned short* __restrict__ Klb) {
  __shared__ __align__(16) unsigned short At[128 * 64];  // 16 KB (features)
  __shared__ __align__(16) unsigned short Bt[256 * 64];  // 32 KB (tokens)
  const int t = threadIdx.x;
  const int lane = t & 63, wave = t >> 6;  // wave 0..7
  const int wf = wave >> 2, wt = wave & 3; // 2 feature-halves x 4 token-quads
  const unsigned int isf = detect_f32((const unsigned short*)xraw);
  const unsigned short* xb = isf ? cx : (const unsigned short*)xraw;
  // T1: bijective chunk swizzle, nwg = 768 = 8 * 96
  const int lin = blockIdx.x + blockIdx.y * 12;
  const int swz = (lin & 7) * 96 + (lin >> 3);
  const int f0 = (swz % 12) * 128, n0g = (swz / 12) * 256;
  const int srow = lane >> 3, skc = ((lane & 7) ^ srow) * 8;  // swizzled src
  const int fr = lane & 15, fq = lane >> 4;
  const int rsw = fr & 7;  // read-side swizzle key (row & 7)
  f32x4 acc[4][4] = {};

  for (int k0 = 0; k0 < 512; k0 += 64) {
#pragma unroll
    for (int s = 0; s < 2; s++) {  // At: 16 instr total, 2 per wave
      int inst = wave * 2 + s;
      int row = inst * 8 + srow;
      gload_lds16(w + (size_t)(f0 + row) * 512 + k0 + skc, &At[inst * 512]);
    }
#pragma unroll
    for (int s = 0; s < 4; s++) {  // Bt: 32 instr total, 4 per wave
      int inst = wave * 4 + s;
      int row = inst * 8 + srow;
      gload_lds16(xb + (size_t)(n0g + row) * 512 + k0 + skc, &Bt[inst * 512]);
    }
    __syncthreads();
#pragma unroll
    for (int kk = 0; kk < 64; kk += 32) {
      const int swo = (((kk >> 3) + fq) ^ rsw) << 3;
      bf16x8 af[4], bxf[4];
#pragma unroll
      for (int i = 0; i < 4; i++)
        af[i] = *(const bf16x8*)&At[(wf * 64 + i * 16 + fr) * 64 + swo];
#pragma unroll
      for (int j = 0; j < 4; j++)
        bxf[j] = *(const bf16x8*)&Bt[(wt * 64 + j * 16 + fr) * 64 + swo];
#pragma unroll
      for (int i = 0; i < 4; i++)
#pragma unroll
        for (int j = 0; j < 4; j++)
          acc[i][j] = __builtin_amdgcn_mfma_f32_16x16x32_bf16(
              af[i], bxf[j], acc[i][j], 0, 0, 0);
    }
    __syncthreads();
  }
  // epilogue: wave-uniform (which, h); rows = features, cols = tokens
  const int fbase = f0 + wf * 64;
  const int which = fbase >> 9;
  const int h = (fbase >> 6) & 7;
  const float scale = (which < 2) ? 0.3535533905932738f : 1.0f;
  const int b_ = n0g >> 12;
  const int bh = b_ * 8 + h;
  const int m_loc = ((n0g + wt * 64) & 4095) >> 6;  // landmark (wave-uniform)
#pragma unroll
  for (int i = 0; i < 4; i++) {
    int d0 = i * 16 + fq * 4;
#pragma unroll
    for (int j = 0; j < 4; j++) {
      int nn = (n0g + wt * 64 + j * 16 + fr) & 4095;
      unsigned short pack[4];
#pragma unroll
      for (int r = 0; r < 4; r++) pack[r] = f2bf(acc[i][j][r] * scale);
      *(uint2*)&qkv[(size_t)which * QSZe + ((size_t)bh * 4096 + nn) * 64 +
                    d0] = *(const uint2*)pack;
    }
  }
  if (which < 2) {  // fused landmark pooling (mean over this wave's 64 tokens)
    const float ps = scale * (1.0f / 64.0f);
#pragma unroll
    for (int i = 0; i < 4; i++) {
      float sm[4];
#pragma unroll
      for (int r = 0; r < 4; r++)
        sm[r] = acc[i][0][r] + acc[i][1][r] + acc[i][2][r] + acc[i][3][r];
#pragma unroll
      for (int mask = 1; mask < 16; mask <<= 1)
#pragma unroll
        for (int r = 0; r < 4; r++) sm[r] += __shfl_xor(sm[r], mask, 64);
      if (fr == 0) {
        int d0 = i * 16 + fq * 4;
        float4 v4 = make_float4(sm[0] * ps, sm[1] * ps, sm[2] * ps, sm[3] * ps);
        unsigned short pk[4] = {f2bf(v4.x), f2bf(v4.y), f2bf(v4.z), f2bf(v4.w)};
        size_t off = (size_t)bh * 4096 + m_loc * 64 + d0;
        if (which == 0) {
          *(float4*)&Ql[off] = v4;
          *(uint2*)&Qlb[off] = *(const uint2*)pk;
        } else {
          *(float4*)&Kl[off] = v4;
          *(uint2*)&Klb[off] = *(const uint2*)pk;
        }
      }
    }
  }
}

// ---------------------------------------------------------------------------
// Kernel E+C fused: slab<8 -> kernel_3 + P@V partials (k3 body);
// slab==8 -> kernel_2 softmax + global colsum/rowsum max (k2 body).
// Grid (9, 32 bh), 256 thr.  LDS aliased in one 35840 B buffer.
// ---------------------------------------------------------------------------
__global__ __launch_bounds__(256) void k3k2_mfma(
    const unsigned short* __restrict__ Qlb,
    const unsigned short* __restrict__ qkv, float* __restrict__ Wp,
    float* __restrict__ sp, const float* __restrict__ Ql,
    const float* __restrict__ Kl, float* __restrict__ k2,
    unsigned int* __restrict__ gstat) {
  __shared__ __align__(16) unsigned char SM[35840];
  const int t = threadIdx.x;
  const int lane = t & 63, wave = t >> 6;
  const int slab = blockIdx.x, bh = blockIdx.y;

  if (slab == 8) {  // ------------------ k2 body ------------------
    float* KlT = (float*)SM;           // [d][l] 16384 B
    float* Ps = (float*)(SM + 16384);  // [64][65] 16640 B
#pragma unroll
    for (int i = 0; i < 16; i++) {
      int idx = i * 256 + t;
      KlT[(idx & 63) * 64 + (idx >> 6)] = Kl[bh * 4096 + idx];
    }
    __syncthreads();
    for (int r = wave * 16; r < wave * 16 + 16; r++) {
      float qv = Ql[(bh * 64 + r) * 64 + lane];
      float acc = 0.f;
#pragma unroll
      for (int k = 0; k < 64; k++)
        acc += __shfl(qv, k, 64) * KlT[k * 64 + lane];
      float mx = acc;
#pragma unroll
      for (int o = 32; o > 0; o >>= 1) mx = fmaxf(mx, __shfl_xor(mx, o, 64));
      float e = __expf(acc - mx);
      float s = e;
#pragma unroll
      for (int o = 32; o > 0; o >>= 1) s += __shfl_xor(s, o, 64);
      float p = e / s;
      k2[(bh * 64 + r) * 64 + lane] = p;
      Ps[r * 65 + lane] = p;
    }
    __syncthreads();
    float val = 0.f;
    if (t < 64) {
      for (int r = 0; r < 64; r++) val += Ps[r * 65 + t];  // column sums
    } else if (t < 128) {
      int r = t - 64;
      for (int c = 0; c < 64; c++) val += Ps[r * 65 + c];  // row sums
    }
    float mv = val;
#pragma unroll
    for (int o = 32; o > 0; o >>= 1) mv = fmaxf(mv, __shfl_xor(mv, o, 64));
    if (t == 0) atomicMax(gstat + 0, __float_as_uint(mv));
    if (t == 64) atomicMax(gstat + 1, __float_as_uint(mv));
    return;
  }
  // ------------------ k3 body ------------------
  unsigned short* Et = (unsigned short*)SM;            // [m][n] 17408 B
  unsigned short* Vt = (unsigned short*)(SM + 17408);  // [d][n] 17408 B
  float* scol_l = (float*)(SM + 34816);                // [4][64] 1024 B
  const int fr = lane & 15, fq = lane >> 4;
  const int n_base = slab * 512;
  const unsigned short* Kb = qkv + QSZe + (size_t)bh * 262144;
  const unsigned short* Vb = qkv + 2 * QSZe + (size_t)bh * 262144;
  const unsigned short* Qlp = Qlb + bh * 4096;

  bf16x8 qb[2][4];
#pragma unroll
  for (int h = 0; h < 2; h++)
#pragma unroll
    for (int j = 0; j < 4; j++)
      qb[h][j] = *(const bf16x8*)(Qlp + (j * 16 + fr) * 64 + h * 32 + fq * 8);

  f32x4 accW[4] = {};
  float scol[4] = {0.f, 0.f, 0.f, 0.f};

  for (int sc = 0; sc < 4; sc++) {
    const int n0 = n_base + sc * 128;
    {
      int n = t & 127, dg = t >> 7;
#pragma unroll
      for (int i = 0; i < 4; i++) {
        int d0 = (dg + 2 * i) * 8;
        uint4 v = *(const uint4*)(Vb + (size_t)(n0 + n) * 64 + d0);
        const unsigned short* s = (const unsigned short*)&v;
#pragma unroll
        for (int u = 0; u < 8; u++) Vt[(d0 + u) * 136 + n] = s[u];
      }
    }
    f32x4 acc[2][4] = {};
#pragma unroll
    for (int i = 0; i < 2; i++) {
      const unsigned short* Kr =
          Kb + (size_t)(n0 + wave * 32 + i * 16 + fr) * 64;
      bf16x8 a0 = *(const bf16x8*)(Kr + fq * 8);
      bf16x8 a1 = *(const bf16x8*)(Kr + 32 + fq * 8);
#pragma unroll
      for (int j = 0; j < 4; j++) {
        acc[i][j] = __builtin_amdgcn_mfma_f32_16x16x32_bf16(a0, qb[0][j],
                                                            acc[i][j], 0, 0, 0);
        acc[i][j] = __builtin_amdgcn_mfma_f32_16x16x32_bf16(a1, qb[1][j],
                                                            acc[i][j], 0, 0, 0);
      }
    }
#pragma unroll
    for (int i = 0; i < 2; i++)
#pragma unroll
      for (int j = 0; j < 4; j++) {
        unsigned short pack[4];
        float s4 = 0.f;
#pragma unroll
        for (int r = 0; r < 4; r++) {
          float e = __expf(acc[i][j][r]);
          s4 += e;
          pack[r] = f2bf(e);
        }
        scol[j] += s4;
        *(uint2*)&Et[(j * 16 + fr) * 136 + wave * 32 + i * 16 + fq * 4] =
            *(const uint2*)pack;
      }
    __syncthreads();
#pragma unroll
    for (int kk = 0; kk < 128; kk += 32) {
      bf16x8 ap = *(const bf16x8*)&Et[(wave * 16 + fr) * 136 + kk + fq * 8];
#pragma unroll
      for (int j = 0; j < 4; j++) {
        bf16x8 bv = *(const bf16x8*)&Vt[(j * 16 + fr) * 136 + kk + fq * 8];
        accW[j] =
            __builtin_amdgcn_mfma_f32_16x16x32_bf16(ap, bv, accW[j], 0, 0, 0);
      }
    }
    __syncthreads();
  }
#pragma unroll
  for (int j = 0; j < 4; j++) {
    float s = scol[j];
    s += __shfl_xor(s, 16, 64);
    s += __shfl_xor(s, 32, 64);
    if (fq == 0) scol_l[wave * 64 + j * 16 + fr] = s;
  }
  __syncthreads();
  if (t < 64)
    sp[(bh * 8 + slab) * 64 + t] = scol_l[0 * 64 + t] + scol_l[1 * 64 + t] +
                                   scol_l[2 * 64 + t] + scol_l[3 * 64 + t];
  float* wpo = Wp + ((size_t)bh * 8 + slab) * 4096;
#pragma unroll
  for (int j = 0; j < 4; j++)
#pragma unroll
    for (int r = 0; r < 4; r++)
      wpo[(wave * 16 + fq * 4 + r) * 64 + j * 16 + fr] = accW[j][r];
}

// ---------------------------------------------------------------------------
// Kernel D (MFMA): Newton-Schulz (6 iters) + FUSED k3 reduction (W from
// Wp/sp) + Z^T -> Ztb[bh][d][m] bf16.  One block per (b,h).
// One barrier per mmB.
// ---------------------------------------------------------------------------
__global__ __launch_bounds__(256) void ns_kernel(
    const float* __restrict__ k2g, const unsigned int* __restrict__ gstat,
    const float* __restrict__ Wp, const float* __restrict__ sp,
    unsigned short* __restrict__ Ztb) {
  __shared__ __align__(16) unsigned short L[8 * 4096];
  __shared__ float ssum[64];
  unsigned short* K2R = L;
  unsigned short* VR = L + 4096;
  unsigned short* VT = L + 2 * 4096;
  unsigned short* AR = L + 3 * 4096;
  unsigned short* AT = L + 4 * 4096;
  unsigned short* T2T = L + 5 * 4096;
  unsigned short* T3T = L + 6 * 4096;
  unsigned short* WT = L + 7 * 4096;
  const int t = threadIdx.x, bh = blockIdx.x;
  const int lane = t & 63, wave = t >> 6;
  const float scale =
      1.0f / (__uint_as_float(gstat[0]) * __uint_as_float(gstat[1]));
  const float* k2p = k2g + bh * 4096;
  if (t < 64) {
    float s = 0.f;
#pragma unroll
    for (int c = 0; c < 8; c++) s += sp[(bh * 8 + c) * 64 + t];
    ssum[t] = s;
  }
  __syncthreads();
#pragma unroll
  for (int i = 0; i < 16; i++) {
    int idx = i * 256 + t;
    int m = idx >> 6, d = idx & 63;
    float kv = k2p[idx];
    K2R[idx] = f2bf(kv);
    VT[idx] = f2bf(kv * scale);
    VR[idx] = f2bf(k2p[d * 64 + m] * scale);
    float wv = 0.f;
#pragma unroll
    for (int cc = 0; cc < 8; cc++)
      wv += Wp[((size_t)(bh * 8 + cc)) * 4096 + idx];
    WT[d * 64 + m] = f2bf(wv / ssum[m]);
  }
  __syncthreads();
  for (int it = 0; it < 6; it++) {
    mmB(K2R, VT, AR, AT, wave, lane, 1.0f, 0.0f, 0.0f, nullptr);
    __syncthreads();
    mmB(AR, AT, nullptr, T2T, wave, lane, 1.0f, 15.0f, -7.0f, AR);
    __syncthreads();
    mmB(AR, T2T, nullptr, T3T, wave, lane, -1.0f, 13.0f, 0.0f, nullptr);
    __syncthreads();
    mmB(VR, T3T, VR, VT, wave, lane, 0.25f, 0.0f, 0.0f, nullptr);
    __syncthreads();
  }
  {
    const int fr = lane & 15, fq = lane >> 4;
    bf16x8 af0 = *(const bf16x8*)&WT[(wave * 16 + fr) * 64 + fq * 8];
    bf16x8 af1 = *(const bf16x8*)&WT[(wave * 16 + fr) * 64 + 32 + fq * 8];
    f32x4 acc[4] = {};
#pragma unroll
    for (int j = 0; j < 4; j++) {
      bf16x8 b0 = *(const bf16x8*)&VR[(j * 16 + fr) * 64 + fq * 8];
      bf16x8 b1 = *(const bf16x8*)&VR[(j * 16 + fr) * 64 + 32 + fq * 8];
      acc[j] =
          __builtin_amdgcn_mfma_f32_16x16x32_bf16(af0, b0, acc[j], 0, 0, 0);
      acc[j] =
          __builtin_amdgcn_mfma_f32_16x16x32_bf16(af1, b1, acc[j], 0, 0, 0);
    }
#pragma unroll
    for (int j = 0; j < 4; j++) {
      int m = j * 16 + fr;
#pragma unroll
      for (int r = 0; r < 4; r++) {
        int d = wave * 16 + fq * 4 + r;
        Ztb[bh * 4096 + d * 64 + m] = f2bf(acc[j][r]);
      }
    }
  }
}

// ---------------------------------------------------------------------------
// Kernel G (MFMA): kernel_1 softmax fused with X = P @ Z. Grid (32, 32).
// Qt tile XOR-swizzled (Ps already 72-padded: conflict-free).
// ---------------------------------------------------------------------------
__global__ __launch_bounds__(256) void k1x_mfma(
    const unsigned short* __restrict__ qkv,
    const unsigned short* __restrict__ Klb,
    const unsigned short* __restrict__ Ztb, unsigned short* __restrict__ X) {
  __shared__ __align__(16) unsigned short Qt[128 * 64];  // 16 KB
  __shared__ __align__(16) unsigned short Ps[128 * 72];  // 18 KB
  const int t = threadIdx.x;
  const int lane = t & 63, wave = t >> 6;
  const int fr = lane & 15, fq = lane >> 4;
  const int rsw = fr & 7;
  const int bh = blockIdx.x;
  const int n0 = blockIdx.y * 128;
  const unsigned short* Qb = qkv + (size_t)bh * 262144 + (size_t)n0 * 64;
  const unsigned short* Klp = Klb + bh * 4096;
  const unsigned short* Ztp = Ztb + bh * 4096;

  {
    const int srow = lane >> 3, skc = ((lane & 7) ^ srow) * 8;  // swizzled src
#pragma unroll
    for (int s = 0; s < 4; s++) {
      int inst = wave * 4 + s;
      gload_lds16(Qb + (size_t)(inst * 8 + srow) * 64 + skc, &Qt[inst * 512]);
    }
  }
  __syncthreads();

  f32x4 acc[2][4] = {};
#pragma unroll
  for (int kk = 0; kk < 64; kk += 32) {
    bf16x8 af[2], bg[4];
#pragma unroll
    for (int i = 0; i < 2; i++)
      af[i] = *(const bf16x8*)&Qt[(wave * 32 + i * 16 + fr) * 64 +
                                  ((((kk >> 3) + fq) ^ rsw) << 3)];
#pragma unroll
    for (int j = 0; j < 4; j++)
      bg[j] = *(const bf16x8*)(Klp + (j * 16 + fr) * 64 + kk + fq * 8);
#pragma unroll
    for (int i = 0; i < 2; i++)
#pragma unroll
      for (int j = 0; j < 4; j++)
        acc[i][j] = __builtin_amdgcn_mfma_f32_16x16x32_bf16(af[i], bg[j],
                                                            acc[i][j], 0, 0, 0);
  }

#pragma unroll
  for (int i = 0; i < 2; i++) {
    float sr[4] = {0.f, 0.f, 0.f, 0.f};
#pragma unroll
    for (int j = 0; j < 4; j++)
#pragma unroll
      for (int r = 0; r < 4; r++) {
        float e = __expf(acc[i][j][r]);
        acc[i][j][r] = e;
        sr[r] += e;
      }
#pragma unroll
    for (int mask = 1; mask < 16; mask <<= 1)
#pragma unroll
      for (int r = 0; r < 4; r++) sr[r] += __shfl_xor(sr[r], mask, 64);
    float is[4];
#pragma unroll
    for (int r = 0; r < 4; r++) is[r] = 1.0f / sr[r];
#pragma unroll
    for (int j = 0; j < 4; j++)
#pragma unroll
      for (int r = 0; r < 4; r++)
        Ps[(wave * 32 + i * 16 + fq * 4 + r) * 72 + j * 16 + fr] =
            f2bf(acc[i][j][r] * is[r]);
  }
  __syncthreads();

  f32x4 ax[2][4] = {};
#pragma unroll
  for (int kk = 0; kk < 64; kk += 32) {
    bf16x8 ap[2], bz[4];
#pragma unroll
    for (int i = 0; i < 2; i++)
      ap[i] =
          *(const bf16x8*)&Ps[(wave * 32 + i * 16 + fr) * 72 + kk + fq * 8];
#pragma unroll
    for (int j = 0; j < 4; j++)
      bz[j] = *(const bf16x8*)(Ztp + (j * 16 + fr) * 64 + kk + fq * 8);
#pragma unroll
    for (int i = 0; i < 2; i++)
#pragma unroll
      for (int j = 0; j < 4; j++)
        ax[i][j] = __builtin_amdgcn_mfma_f32_16x16x32_bf16(ap[i], bz[j],
                                                           ax[i][j], 0, 0, 0);
  }

  const int b_ = bh >> 3, h = bh & 7;
#pragma unroll
  for (int i = 0; i < 2; i++) {
#pragma unroll
    for (int j = 0; j < 4; j++) {
      int c = h * 64 + j * 16 + fr;
#pragma unroll
      for (int r = 0; r < 4; r++) {
        int n = n0 + wave * 32 + i * 16 + fq * 4 + r;
        X[((size_t)(b_ * 4096 + n)) * 512 + c] = f2bf(ax[i][j][r]);
      }
    }
  }
}

// ---------------------------------------------------------------------------
// Kernel H (MFMA): out = X @ proj_w^T + proj_b, fp32 OUT. Grid (4, 128).
// Round-1 block mapping (no T1), T2 swizzle, single buffer.
// Bias converted inline (self-detect dtype).
// ---------------------------------------------------------------------------
__global__ __launch_bounds__(256) void proj_gemm_mfma(
    const unsigned short* __restrict__ X, const unsigned short* __restrict__ w,
    const unsigned short* __restrict__ raw_x, const void* __restrict__ raw_b,
    float* __restrict__ out) {
  __shared__ __align__(16) unsigned short At[128 * 64];
  __shared__ __align__(16) unsigned short Bt[128 * 64];
  const int t = threadIdx.x;
  const unsigned int f = detect_f32(raw_x);
  const int lane = t & 63, wave = t >> 6;
  const int wr = wave >> 1, wc = wave & 1;
  const int i0 = blockIdx.y * 128, j0 = blockIdx.x * 128;
  const int srow = lane >> 3;
  const int skc = ((lane & 7) ^ srow) * 8;  // swizzled src
  const int fr = lane & 15, fq = lane >> 4;
  const int rsw = fr & 7;
  f32x4 acc[4][4] = {};

  for (int k0 = 0; k0 < 512; k0 += 64) {
#pragma unroll
    for (int s = 0; s < 4; s++) {
      int inst = wave * 4 + s;
      int row = inst * 8 + srow;
      gload_lds16(X + (size_t)(i0 + row) * 512 + k0 + skc, &At[inst * 512]);
      gload_lds16(w + (size_t)(j0 + row) * 512 + k0 + skc, &Bt[inst * 512]);
    }
    __syncthreads();
#pragma unroll
    for (int kk = 0; kk < 64; kk += 32) {
      const int swo = (((kk >> 3) + fq) ^ rsw) << 3;
      bf16x8 af[4], bg[4];
#pragma unroll
      for (int i = 0; i < 4; i++)
        af[i] = *(const bf16x8*)&At[(wr * 64 + i * 16 + fr) * 64 + swo];
#pragma unroll
      for (int j = 0; j < 4; j++)
        bg[j] = *(const bf16x8*)&Bt[(wc * 64 + j * 16 + fr) * 64 + swo];
#pragma unroll
      for (int i = 0; i < 4; i++)
#pragma unroll
        for (int j = 0; j < 4; j++)
          acc[i][j] = __builtin_amdgcn_mfma_f32_16x16x32_bf16(
              af[i], bg[j], acc[i][j], 0, 0, 0);
    }
    __syncthreads();
  }
#pragma unroll
  for (int j = 0; j < 4; j++) {
    int col = j0 + wc * 64 + j * 16 + fr;  // 0..511
    float bia = f ? ((const float*)raw_b)[col]
                  : bf2f(((const unsigned short*)raw_b)[col]);
#pragma unroll
    for (int i = 0; i < 4; i++) {
      int rbase = i0 + wr * 64 + i * 16 + fq * 4;
#pragma unroll
      for (int r = 0; r < 4; r++) {
        out[(size_t)(rbase + r) * 512 + col] = acc[i][j][r] + bia;
      }
    }
  }
}

// ---------------------------------------------------------------------------
extern "C" void kernel_launch(void* const* d_in, const int* in_sizes, int n_in,
                              void* d_out, int out_size, void* d_ws,
                              size_t ws_size, hipStream_t stream) {
  (void)in_sizes; (void)n_in; (void)out_size; (void)ws_size;

  char* w8 = (char*)d_ws;
  unsigned short* cx  = (unsigned short*)(w8 + 0);         // x canon bf16
  unsigned short* cwq = (unsigned short*)(w8 + 16777216);  // qkv_w canon
  unsigned short* cwp = (unsigned short*)(w8 + 18350080);  // proj_w canon
  unsigned short* qkv = (unsigned short*)(w8 + 18876416);  // Q,K,V bf16
  unsigned short* X   = (unsigned short*)(w8 + 69208064);  // attn out bf16
  float* Ql = (float*)(w8 + 85985280);
  float* Kl = (float*)(w8 + 86509568);
  float* k2 = (float*)(w8 + 87033856);
  unsigned short* Ztb = (unsigned short*)(w8 + 88082432);  // Z^T bf16 [bh][d][m]
  unsigned int* gstat = (unsigned int*)(w8 + 88606720);  // [cmax, rmax]
  float* Wp = (float*)(w8 + 88608768);                   // 32*8*4096*4 B
  float* sp = (float*)(w8 + 92803072);                   // 32*8*64*4 B
  unsigned short* Klb = (unsigned short*)(w8 + 92868608); // Kl bf16
  unsigned short* Qlb = (unsigned short*)(w8 + 93130752); // Ql bf16

  conv_all<<<4608, 256, 0, stream>>>(d_in[0], d_in[1], d_in[2], cx, cwq, cwp,
                                     gstat);
  qkv_gemm_mfma<<<dim3(12, 64), 512, 0, stream>>>(cwq, d_in[0], cx, qkv, Ql,
                                                  Kl, Qlb, Klb);
  k3k2_mfma<<<dim3(9, 32), 256, 0, stream>>>(Qlb, qkv, Wp, sp, Ql, Kl, k2,
                                             gstat);
  ns_kernel<<<32, 256, 0, stream>>>(k2, gstat, Wp, sp, Ztb);
  k1x_mfma<<<dim3(32, 32), 256, 0, stream>>>(qkv, Klb, Ztb, X);
  proj_gemm_mfma<<<dim3(4, 128), 256, 0, stream>>>(
      X, cwp, (const unsigned short*)d_in[0], d_in[3], (float*)d_out);
}

// Round 7
// 223.187 us; speedup vs baseline: 1.0679x; 1.0084x over previous
//
#include <hip/hip_runtime.h>
#include <hip/hip_bf16.h>
#include <stdint.h>

// Problem constants: B=4, N=4096, C=512, H=8, M=64, HD=64
#define QSZe 8388608ull  // elements per Q/K/V tensor (B*H*N*HD)

typedef __attribute__((ext_vector_type(8))) short bf16x8;
typedef __attribute__((ext_vector_type(4))) float f32x4;
typedef const __attribute__((address_space(1))) unsigned int* gas1_t;
typedef __attribute__((address_space(3))) unsigned int* las3_t;

__device__ __forceinline__ float bf2f(unsigned short u) {
  return __uint_as_float(((unsigned int)u) << 16);
}
__device__ __forceinline__ unsigned short f2bf(float f) {
  unsigned int u = __float_as_uint(f);
  unsigned int r = (u + 0x7FFFu + ((u >> 16) & 1u)) >> 16;
  return (unsigned short)r;
}
__device__ __forceinline__ void gload_lds16(const void* g, void* l) {
  __builtin_amdgcn_global_load_lds((gas1_t)g, (las3_t)l, 16, 0, 0);
}
// Per-wave fp32-input detection (same 256 half-words / predicate as the
// original detect_bias).  Wave-uniform result, no barrier needed.
__device__ __forceinline__ unsigned int detect_f32(
    const unsigned short* __restrict__ raw_x) {
  int lane = threadIdx.x & 63;
  int big = 0;
#pragma unroll
  for (int i = 0; i < 4; i++) {
    int e = (raw_x[lane * 4 + i] >> 7) & 0xFF;
    big |= (e >= 0x8F) ? 1 : 0;
  }
  return (__ballot(big) != 0ull) ? 1u : 0u;
}

// ---------------------------------------------------------------------------
// Canonicalize x (only if fp32), qkv_w, proj_w to bf16 in ONE dispatch.
// If input is bf16, the x-region blocks skip the copy entirely (qkv_gemm
// reads raw x directly via pointer select).  Zeroes gstat.  Grid 4608 x 256.
// ---------------------------------------------------------------------------
__global__ __launch_bounds__(256) void conv_all(
    const void* __restrict__ rx, const void* __restrict__ rwq,
    const void* __restrict__ rwp, unsigned short* __restrict__ cx,
    unsigned short* __restrict__ cwq, unsigned short* __restrict__ cwp,
    unsigned int* __restrict__ gstat) {
  int gid = blockIdx.x * 256 + threadIdx.x;
  if (gid == 0) {  // init atomicMax targets for the k2 phase
    gstat[0] = 0u;
    gstat[1] = 0u;
  }
  unsigned int f = detect_f32((const unsigned short*)rx);
  const void* src;
  unsigned short* dst;
  int i8;
  if (gid < 1048576) {
    if (!f) return;  // bf16 input: qkv reads raw x, no copy needed
    src = rx; dst = cx; i8 = gid * 8;
  } else if (gid < 1146880) {
    src = rwq; dst = cwq; i8 = (gid - 1048576) * 8;
  } else {
    src = rwp; dst = cwp; i8 = (gid - 1146880) * 8;
  }
  if (f) {
    const float* fp = (const float*)src;
    float4 a = *(const float4*)(fp + i8);
    float4 b = *(const float4*)(fp + i8 + 4);
    unsigned short o[8] = {f2bf(a.x), f2bf(a.y), f2bf(a.z), f2bf(a.w),
                           f2bf(b.x), f2bf(b.y), f2bf(b.z), f2bf(b.w)};
    *(uint4*)(dst + i8) = *(const uint4*)o;
  } else {
    *(uint4*)(dst + i8) = *(const uint4*)((const unsigned short*)src + i8);
  }
}

// ---------------------------------------------------------------------------
// bf16 MFMA 64x64x64 helper for ns_kernel.  NO internal barrier (caller
// places one after each call; aliasing is safe per r4 analysis).
// ---------------------------------------------------------------------------
__device__ __forceinline__ void mmB(const unsigned short* A_R,
                                    const unsigned short* B_T,
                                    unsigned short* out_R,
                                    unsigned short* out_T, int wave, int lane,
                                    float s, float dg, float a7,
                                    const unsigned short* Aelt) {
  const int fr = lane & 15, fq = lane >> 4;
  bf16x8 af0 = *(const bf16x8*)&A_R[(wave * 16 + fr) * 64 + fq * 8];
  bf16x8 af1 = *(const bf16x8*)&A_R[(wave * 16 + fr) * 64 + 32 + fq * 8];
  f32x4 acc[4] = {};
#pragma unroll
  for (int j = 0; j < 4; j++) {
    bf16x8 b0 = *(const bf16x8*)&B_T[(j * 16 + fr) * 64 + fq * 8];
    bf16x8 b1 = *(const bf16x8*)&B_T[(j * 16 + fr) * 64 + 32 + fq * 8];
    acc[j] = __builtin_amdgcn_mfma_f32_16x16x32_bf16(af0, b0, acc[j], 0, 0, 0);
    acc[j] = __builtin_amdgcn_mfma_f32_16x16x32_bf16(af1, b1, acc[j], 0, 0, 0);
  }
  float ael[4][4];
  if (Aelt) {
#pragma unroll
    for (int j = 0; j < 4; j++)
#pragma unroll
      for (int r = 0; r < 4; r++)
        ael[j][r] = bf2f(Aelt[(wave * 16 + fq * 4 + r) * 64 + j * 16 + fr]);
  }
#pragma unroll
  for (int j = 0; j < 4; j++) {
    int col = j * 16 + fr;
    unsigned short pack[4];
#pragma unroll
    for (int r = 0; r < 4; r++) {
      int row = wave * 16 + fq * 4 + r;
      float v = s * acc[j][r] + ((row == col) ? dg : 0.0f);
      if (Aelt) v += a7 * ael[j][r];
      unsigned short bv = f2bf(v);
      if (out_R) out_R[row * 64 + col] = bv;
      pack[r] = bv;
    }
    if (out_T)
      *(uint2*)&out_T[col * 64 + wave * 16 + fq * 4] = *(const uint2*)pack;
  }
}

// ---------------------------------------------------------------------------
// Kernel A (MFMA, C^T orientation): qkv = x @ qkv_w^T via D = W @ X^T.
// 128f x 256t tile, 8 waves, wave 64x64 (acc[4][4]).  T4 COUNTED-VMCNT
// depth-2 pipeline: both tiles double-buffered (96 KB LDS, 1 block/CU);
// tile t+1's 6 gload_lds per wave issue BEFORE compute of tile t, then
// `s_waitcnt vmcnt(6)` (NOT 0) + raw s_barrier — next tile's loads stay in
// flight under the MFMA phase (vmcnt retires in order, so vmcnt(6) ==
// "my 6 oldest (buf p) loads done"; barrier makes it block-wide).  Raw
// barriers are memory-clobbered inline asm so the compiler neither inserts
// its own vmcnt(0) drain nor hoists ds_reads across.  Barrier-2 after
// COMPUTE protects buffer reuse (ds_reads all consumed via lgkm waits
// before each wave's MFMAs).  T2 XOR-swizzled LDS (both-sides rule #21) +
// T1 XCD chunk swizzle (nwg=768=8*96).  Pooling fused in epilogue.
// Grid (12, 64), 512 thr, 96 KB LDS.
// ---------------------------------------------------------------------------
__global__ __launch_bounds__(512) void qkv_gemm_mfma(
    const unsigned short* __restrict__ w, const void* __restrict__ xraw,
    const unsigned short* __restrict__ cx, unsigned short* __restrict__ qkv,
    float* __restrict__ Ql, float* __restrict__ Kl,
    unsigned short* __restrict__ Qlb, unsigned short* __restrict__ Klb) {
  __shared__ __align__(16) unsigned short At[2][128 * 64];  // 2 x 16 KB
  __shared__ __align__(16) unsigned short Bt[2][256 * 64];  // 2 x 32 KB
  const int t = threadIdx.x;
  const int lane = t & 63, wave = t >> 6;  // wave 0..7
  const int wf = wave >> 2, wt = wave & 3; // 2 feature-halves x 4 token-quads
  const unsigned int isf = detect_f32((const unsigned short*)xraw);
  const unsigned short* xb = isf ? cx : (const unsigned short*)xraw;
  // T1: bijective chunk swizzle, nwg = 768 = 8 * 96
  const int lin = blockIdx.x + blockIdx.y * 12;
  const int swz = (lin & 7) * 96 + (lin >> 3);
  const int f0 = (swz % 12) * 128, n0g = (swz / 12) * 256;
  const int srow = lane >> 3, skc = ((lane & 7) ^ srow) * 8;  // swizzled src
  const int fr = lane & 15, fq = lane >> 4;
  const int rsw = fr & 7;  // read-side swizzle key (row & 7)
  f32x4 acc[4][4] = {};

  auto STAGE = [&](int p, int k0) {
#pragma unroll
    for (int s = 0; s < 2; s++) {  // At: 16 instr total, 2 per wave
      int inst = wave * 2 + s;
      int row = inst * 8 + srow;
      gload_lds16(w + (size_t)(f0 + row) * 512 + k0 + skc,
                  &At[p][inst * 512]);
    }
#pragma unroll
    for (int s = 0; s < 4; s++) {  // Bt: 32 instr total, 4 per wave
      int inst = wave * 4 + s;
      int row = inst * 8 + srow;
      gload_lds16(xb + (size_t)(n0g + row) * 512 + k0 + skc,
                  &Bt[p][inst * 512]);
    }
  };
  auto COMPUTE = [&](int p) {
#pragma unroll
    for (int kk = 0; kk < 64; kk += 32) {
      const int swo = (((kk >> 3) + fq) ^ rsw) << 3;
      bf16x8 af[4], bxf[4];
#pragma unroll
      for (int i = 0; i < 4; i++)
        af[i] = *(const bf16x8*)&At[p][(wf * 64 + i * 16 + fr) * 64 + swo];
#pragma unroll
      for (int j = 0; j < 4; j++)
        bxf[j] = *(const bf16x8*)&Bt[p][(wt * 64 + j * 16 + fr) * 64 + swo];
#pragma unroll
      for (int i = 0; i < 4; i++)
#pragma unroll
        for (int j = 0; j < 4; j++)
          acc[i][j] = __builtin_amdgcn_mfma_f32_16x16x32_bf16(
              af[i], bxf[j], acc[i][j], 0, 0, 0);
    }
  };

  STAGE(0, 0);  // 6 loads/wave in flight
  int p = 0;
#pragma unroll 1
  for (int k0 = 0; k0 < 512; k0 += 64) {
    if (k0 + 64 < 512) {
      STAGE(p ^ 1, k0 + 64);  // +6 loads -> 12 outstanding
      asm volatile("s_waitcnt vmcnt(6)" ::: "memory");  // buf p's 6 done
    } else {
      asm volatile("s_waitcnt vmcnt(0)" ::: "memory");  // last tile: drain
    }
    asm volatile("s_barrier" ::: "memory");  // buf p populated block-wide
    COMPUTE(p);
    asm volatile("s_barrier" ::: "memory");  // all reads of buf p done
    p ^= 1;
  }
  // epilogue: wave-uniform (which, h); rows = features, cols = tokens
  const int fbase = f0 + wf * 64;
  const int which = fbase >> 9;
  const int h = (fbase >> 6) & 7;
  const float scale = (which < 2) ? 0.3535533905932738f : 1.0f;
  const int b_ = n0g >> 12;
  const int bh = b_ * 8 + h;
  const int m_loc = ((n0g + wt * 64) & 4095) >> 6;  // landmark (wave-uniform)
#pragma unroll
  for (int i = 0; i < 4; i++) {
    int d0 = i * 16 + fq * 4;
#pragma unroll
    for (int j = 0; j < 4; j++) {
      int nn = (n0g + wt * 64 + j * 16 + fr) & 4095;
      unsigned short pack[4];
#pragma unroll
      for (int r = 0; r < 4; r++) pack[r] = f2bf(acc[i][j][r] * scale);
      *(uint2*)&qkv[(size_t)which * QSZe + ((size_t)bh * 4096 + nn) * 64 +
                    d0] = *(const uint2*)pack;
    }
  }
  if (which < 2) {  // fused landmark pooling (mean over this wave's 64 tokens)
    const float ps = scale * (1.0f / 64.0f);
#pragma unroll
    for (int i = 0; i < 4; i++) {
      float sm[4];
#pragma unroll
      for (int r = 0; r < 4; r++)
        sm[r] = acc[i][0][r] + acc[i][1][r] + acc[i][2][r] + acc[i][3][r];
#pragma unroll
      for (int mask = 1; mask < 16; mask <<= 1)
#pragma unroll
        for (int r = 0; r < 4; r++) sm[r] += __shfl_xor(sm[r], mask, 64);
      if (fr == 0) {
        int d0 = i * 16 + fq * 4;
        float4 v4 = make_float4(sm[0] * ps, sm[1] * ps, sm[2] * ps, sm[3] * ps);
        unsigned short pk[4] = {f2bf(v4.x), f2bf(v4.y), f2bf(v4.z), f2bf(v4.w)};
        size_t off = (size_t)bh * 4096 + m_loc * 64 + d0;
        if (which == 0) {
          *(float4*)&Ql[off] = v4;
          *(uint2*)&Qlb[off] = *(const uint2*)pk;
        } else {
          *(float4*)&Kl[off] = v4;
          *(uint2*)&Klb[off] = *(const uint2*)pk;
        }
      }
    }
  }
}

// ---------------------------------------------------------------------------
// Kernel E+C fused: slab<8 -> kernel_3 + P@V partials (k3 body);
// slab==8 -> kernel_2 softmax + global colsum/rowsum max (k2 body).
// Grid (9, 32 bh), 256 thr.  LDS aliased in one 35840 B buffer.
// ---------------------------------------------------------------------------
__global__ __launch_bounds__(256) void k3k2_mfma(
    const unsigned short* __restrict__ Qlb,
    const unsigned short* __restrict__ qkv, float* __restrict__ Wp,
    float* __restrict__ sp, const float* __restrict__ Ql,
    const float* __restrict__ Kl, float* __restrict__ k2,
    unsigned int* __restrict__ gstat) {
  __shared__ __align__(16) unsigned char SM[35840];
  const int t = threadIdx.x;
  const int lane = t & 63, wave = t >> 6;
  const int slab = blockIdx.x, bh = blockIdx.y;

  if (slab == 8) {  // ------------------ k2 body ------------------
    float* KlT = (float*)SM;           // [d][l] 16384 B
    float* Ps = (float*)(SM + 16384);  // [64][65] 16640 B
#pragma unroll
    for (int i = 0; i < 16; i++) {
      int idx = i * 256 + t;
      KlT[(idx & 63) * 64 + (idx >> 6)] = Kl[bh * 4096 + idx];
    }
    __syncthreads();
    for (int r = wave * 16; r < wave * 16 + 16; r++) {
      float qv = Ql[(bh * 64 + r) * 64 + lane];
      float acc = 0.f;
#pragma unroll
      for (int k = 0; k < 64; k++)
        acc += __shfl(qv, k, 64) * KlT[k * 64 + lane];
      float mx = acc;
#pragma unroll
      for (int o = 32; o > 0; o >>= 1) mx = fmaxf(mx, __shfl_xor(mx, o, 64));
      float e = __expf(acc - mx);
      float s = e;
#pragma unroll
      for (int o = 32; o > 0; o >>= 1) s += __shfl_xor(s, o, 64);
      float p = e / s;
      k2[(bh * 64 + r) * 64 + lane] = p;
      Ps[r * 65 + lane] = p;
    }
    __syncthreads();
    float val = 0.f;
    if (t < 64) {
      for (int r = 0; r < 64; r++) val += Ps[r * 65 + t];  // column sums
    } else if (t < 128) {
      int r = t - 64;
      for (int c = 0; c < 64; c++) val += Ps[r * 65 + c];  // row sums
    }
    float mv = val;
#pragma unroll
    for (int o = 32; o > 0; o >>= 1) mv = fmaxf(mv, __shfl_xor(mv, o, 64));
    if (t == 0) atomicMax(gstat + 0, __float_as_uint(mv));
    if (t == 64) atomicMax(gstat + 1, __float_as_uint(mv));
    return;
  }
  // ------------------ k3 body ------------------
  unsigned short* Et = (unsigned short*)SM;            // [m][n] 17408 B
  unsigned short* Vt = (unsigned short*)(SM + 17408);  // [d][n] 17408 B
  float* scol_l = (float*)(SM + 34816);                // [4][64] 1024 B
  const int fr = lane & 15, fq = lane >> 4;
  const int n_base = slab * 512;
  const unsigned short* Kb = qkv + QSZe + (size_t)bh * 262144;
  const unsigned short* Vb = qkv + 2 * QSZe + (size_t)bh * 262144;
  const unsigned short* Qlp = Qlb + bh * 4096;

  bf16x8 qb[2][4];
#pragma unroll
  for (int h = 0; h < 2; h++)
#pragma unroll
    for (int j = 0; j < 4; j++)
      qb[h][j] = *(const bf16x8*)(Qlp + (j * 16 + fr) * 64 + h * 32 + fq * 8);

  f32x4 accW[4] = {};
  float scol[4] = {0.f, 0.f, 0.f, 0.f};

  for (int sc = 0; sc < 4; sc++) {
    const int n0 = n_base + sc * 128;
    {
      int n = t & 127, dg = t >> 7;
#pragma unroll
      for (int i = 0; i < 4; i++) {
        int d0 = (dg + 2 * i) * 8;
        uint4 v = *(const uint4*)(Vb + (size_t)(n0 + n) * 64 + d0);
        const unsigned short* s = (const unsigned short*)&v;
#pragma unroll
        for (int u = 0; u < 8; u++) Vt[(d0 + u) * 136 + n] = s[u];
      }
    }
    f32x4 acc[2][4] = {};
#pragma unroll
    for (int i = 0; i < 2; i++) {
      const unsigned short* Kr =
          Kb + (size_t)(n0 + wave * 32 + i * 16 + fr) * 64;
      bf16x8 a0 = *(const bf16x8*)(Kr + fq * 8);
      bf16x8 a1 = *(const bf16x8*)(Kr + 32 + fq * 8);
#pragma unroll
      for (int j = 0; j < 4; j++) {
        acc[i][j] = __builtin_amdgcn_mfma_f32_16x16x32_bf16(a0, qb[0][j],
                                                            acc[i][j], 0, 0, 0);
        acc[i][j] = __builtin_amdgcn_mfma_f32_16x16x32_bf16(a1, qb[1][j],
                                                            acc[i][j], 0, 0, 0);
      }
    }
#pragma unroll
    for (int i = 0; i < 2; i++)
#pragma unroll
      for (int j = 0; j < 4; j++) {
        unsigned short pack[4];
        float s4 = 0.f;
#pragma unroll
        for (int r = 0; r < 4; r++) {
          float e = __expf(acc[i][j][r]);
          s4 += e;
          pack[r] = f2bf(e);
        }
        scol[j] += s4;
        *(uint2*)&Et[(j * 16 + fr) * 136 + wave * 32 + i * 16 + fq * 4] =
            *(const uint2*)pack;
      }
    __syncthreads();
#pragma unroll
    for (int kk = 0; kk < 128; kk += 32) {
      bf16x8 ap = *(const bf16x8*)&Et[(wave * 16 + fr) * 136 + kk + fq * 8];
#pragma unroll
      for (int j = 0; j < 4; j++) {
        bf16x8 bv = *(const bf16x8*)&Vt[(j * 16 + fr) * 136 + kk + fq * 8];
        accW[j] =
            __builtin_amdgcn_mfma_f32_16x16x32_bf16(ap, bv, accW[j], 0, 0, 0);
      }
    }
    __syncthreads();
  }
#pragma unroll
  for (int j = 0; j < 4; j++) {
    float s = scol[j];
    s += __shfl_xor(s, 16, 64);
    s += __shfl_xor(s, 32, 64);
    if (fq == 0) scol_l[wave * 64 + j * 16 + fr] = s;
  }
  __syncthreads();
  if (t < 64)
    sp[(bh * 8 + slab) * 64 + t] = scol_l[0 * 64 + t] + scol_l[1 * 64 + t] +
                                   scol_l[2 * 64 + t] + scol_l[3 * 64 + t];
  float* wpo = Wp + ((size_t)bh * 8 + slab) * 4096;
#pragma unroll
  for (int j = 0; j < 4; j++)
#pragma unroll
    for (int r = 0; r < 4; r++)
      wpo[(wave * 16 + fq * 4 + r) * 64 + j * 16 + fr] = accW[j][r];
}

// ---------------------------------------------------------------------------
// Kernel D (MFMA): Newton-Schulz (6 iters) + FUSED k3 reduction (W from
// Wp/sp) + Z^T -> Ztb[bh][d][m] bf16.  One block per (b,h).
// One barrier per mmB.
// ---------------------------------------------------------------------------
__global__ __launch_bounds__(256) void ns_kernel(
    const float* __restrict__ k2g, const unsigned int* __restrict__ gstat,
    const float* __restrict__ Wp, const float* __restrict__ sp,
    unsigned short* __restrict__ Ztb) {
  __shared__ __align__(16) unsigned short L[8 * 4096];
  __shared__ float ssum[64];
  unsigned short* K2R = L;
  unsigned short* VR = L + 4096;
  unsigned short* VT = L + 2 * 4096;
  unsigned short* AR = L + 3 * 4096;
  unsigned short* AT = L + 4 * 4096;
  unsigned short* T2T = L + 5 * 4096;
  unsigned short* T3T = L + 6 * 4096;
  unsigned short* WT = L + 7 * 4096;
  const int t = threadIdx.x, bh = blockIdx.x;
  const int lane = t & 63, wave = t >> 6;
  const float scale =
      1.0f / (__uint_as_float(gstat[0]) * __uint_as_float(gstat[1]));
  const float* k2p = k2g + bh * 4096;
  if (t < 64) {
    float s = 0.f;
#pragma unroll
    for (int c = 0; c < 8; c++) s += sp[(bh * 8 + c) * 64 + t];
    ssum[t] = s;
  }
  __syncthreads();
#pragma unroll
  for (int i = 0; i < 16; i++) {
    int idx = i * 256 + t;
    int m = idx >> 6, d = idx & 63;
    float kv = k2p[idx];
    K2R[idx] = f2bf(kv);
    VT[idx] = f2bf(kv * scale);
    VR[idx] = f2bf(k2p[d * 64 + m] * scale);
    float wv = 0.f;
#pragma unroll
    for (int cc = 0; cc < 8; cc++)
      wv += Wp[((size_t)(bh * 8 + cc)) * 4096 + idx];
    WT[d * 64 + m] = f2bf(wv / ssum[m]);
  }
  __syncthreads();
  for (int it = 0; it < 6; it++) {
    mmB(K2R, VT, AR, AT, wave, lane, 1.0f, 0.0f, 0.0f, nullptr);
    __syncthreads();
    mmB(AR, AT, nullptr, T2T, wave, lane, 1.0f, 15.0f, -7.0f, AR);
    __syncthreads();
    mmB(AR, T2T, nullptr, T3T, wave, lane, -1.0f, 13.0f, 0.0f, nullptr);
    __syncthreads();
    mmB(VR, T3T, VR, VT, wave, lane, 0.25f, 0.0f, 0.0f, nullptr);
    __syncthreads();
  }
  {
    const int fr = lane & 15, fq = lane >> 4;
    bf16x8 af0 = *(const bf16x8*)&WT[(wave * 16 + fr) * 64 + fq * 8];
    bf16x8 af1 = *(const bf16x8*)&WT[(wave * 16 + fr) * 64 + 32 + fq * 8];
    f32x4 acc[4] = {};
#pragma unroll
    for (int j = 0; j < 4; j++) {
      bf16x8 b0 = *(const bf16x8*)&VR[(j * 16 + fr) * 64 + fq * 8];
      bf16x8 b1 = *(const bf16x8*)&VR[(j * 16 + fr) * 64 + 32 + fq * 8];
      acc[j] =
          __builtin_amdgcn_mfma_f32_16x16x32_bf16(af0, b0, acc[j], 0, 0, 0);
      acc[j] =
          __builtin_amdgcn_mfma_f32_16x16x32_bf16(af1, b1, acc[j], 0, 0, 0);
    }
#pragma unroll
    for (int j = 0; j < 4; j++) {
      int m = j * 16 + fr;
#pragma unroll
      for (int r = 0; r < 4; r++) {
        int d = wave * 16 + fq * 4 + r;
        Ztb[bh * 4096 + d * 64 + m] = f2bf(acc[j][r]);
      }
    }
  }
}

// ---------------------------------------------------------------------------
// Kernel G (MFMA): kernel_1 softmax fused with X = P @ Z. Grid (32, 32).
// Qt tile XOR-swizzled (Ps already 72-padded: conflict-free).
// ---------------------------------------------------------------------------
__global__ __launch_bounds__(256) void k1x_mfma(
    const unsigned short* __restrict__ qkv,
    const unsigned short* __restrict__ Klb,
    const unsigned short* __restrict__ Ztb, unsigned short* __restrict__ X) {
  __shared__ __align__(16) unsigned short Qt[128 * 64];  // 16 KB
  __shared__ __align__(16) unsigned short Ps[128 * 72];  // 18 KB
  const int t = threadIdx.x;
  const int lane = t & 63, wave = t >> 6;
  const int fr = lane & 15, fq = lane >> 4;
  const int rsw = fr & 7;
  const int bh = blockIdx.x;
  const int n0 = blockIdx.y * 128;
  const unsigned short* Qb = qkv + (size_t)bh * 262144 + (size_t)n0 * 64;
  const unsigned short* Klp = Klb + bh * 4096;
  const unsigned short* Ztp = Ztb + bh * 4096;

  {
    const int srow = lane >> 3, skc = ((lane & 7) ^ srow) * 8;  // swizzled src
#pragma unroll
    for (int s = 0; s < 4; s++) {
      int inst = wave * 4 + s;
      gload_lds16(Qb + (size_t)(inst * 8 + srow) * 64 + skc, &Qt[inst * 512]);
    }
  }
  __syncthreads();

  f32x4 acc[2][4] = {};
#pragma unroll
  for (int kk = 0; kk < 64; kk += 32) {
    bf16x8 af[2], bg[4];
#pragma unroll
    for (int i = 0; i < 2; i++)
      af[i] = *(const bf16x8*)&Qt[(wave * 32 + i * 16 + fr) * 64 +
                                  ((((kk >> 3) + fq) ^ rsw) << 3)];
#pragma unroll
    for (int j = 0; j < 4; j++)
      bg[j] = *(const bf16x8*)(Klp + (j * 16 + fr) * 64 + kk + fq * 8);
#pragma unroll
    for (int i = 0; i < 2; i++)
#pragma unroll
      for (int j = 0; j < 4; j++)
        acc[i][j] = __builtin_amdgcn_mfma_f32_16x16x32_bf16(af[i], bg[j],
                                                            acc[i][j], 0, 0, 0);
  }

#pragma unroll
  for (int i = 0; i < 2; i++) {
    float sr[4] = {0.f, 0.f, 0.f, 0.f};
#pragma unroll
    for (int j = 0; j < 4; j++)
#pragma unroll
      for (int r = 0; r < 4; r++) {
        float e = __expf(acc[i][j][r]);
        acc[i][j][r] = e;
        sr[r] += e;
      }
#pragma unroll
    for (int mask = 1; mask < 16; mask <<= 1)
#pragma unroll
      for (int r = 0; r < 4; r++) sr[r] += __shfl_xor(sr[r], mask, 64);
    float is[4];
#pragma unroll
    for (int r = 0; r < 4; r++) is[r] = 1.0f / sr[r];
#pragma unroll
    for (int j = 0; j < 4; j++)
#pragma unroll
      for (int r = 0; r < 4; r++)
        Ps[(wave * 32 + i * 16 + fq * 4 + r) * 72 + j * 16 + fr] =
            f2bf(acc[i][j][r] * is[r]);
  }
  __syncthreads();

  f32x4 ax[2][4] = {};
#pragma unroll
  for (int kk = 0; kk < 64; kk += 32) {
    bf16x8 ap[2], bz[4];
#pragma unroll
    for (int i = 0; i < 2; i++)
      ap[i] =
          *(const bf16x8*)&Ps[(wave * 32 + i * 16 + fr) * 72 + kk + fq * 8];
#pragma unroll
    for (int j = 0; j < 4; j++)
      bz[j] = *(const bf16x8*)(Ztp + (j * 16 + fr) * 64 + kk + fq * 8);
#pragma unroll
    for (int i = 0; i < 2; i++)
#pragma unroll
      for (int j = 0; j < 4; j++)
        ax[i][j] = __builtin_amdgcn_mfma_f32_16x16x32_bf16(ap[i], bz[j],
                                                           ax[i][j], 0, 0, 0);
  }

  const int b_ = bh >> 3, h = bh & 7;
#pragma unroll
  for (int i = 0; i < 2; i++) {
#pragma unroll
    for (int j = 0; j < 4; j++) {
      int c = h * 64 + j * 16 + fr;
#pragma unroll
      for (int r = 0; r < 4; r++) {
        int n = n0 + wave * 32 + i * 16 + fq * 4 + r;
        X[((size_t)(b_ * 4096 + n)) * 512 + c] = f2bf(ax[i][j][r]);
      }
    }
  }
}

// ---------------------------------------------------------------------------
// Kernel H (MFMA): out = X @ proj_w^T + proj_b, fp32 OUT. Grid (4, 128).
// Round-1 block mapping (no T1), T2 swizzle, single buffer.
// Bias converted inline (self-detect dtype).
// ---------------------------------------------------------------------------
__global__ __launch_bounds__(256) void proj_gemm_mfma(
    const unsigned short* __restrict__ X, const unsigned short* __restrict__ w,
    const unsigned short* __restrict__ raw_x, const void* __restrict__ raw_b,
    float* __restrict__ out) {
  __shared__ __align__(16) unsigned short At[128 * 64];
  __shared__ __align__(16) unsigned short Bt[128 * 64];
  const int t = threadIdx.x;
  const unsigned int f = detect_f32(raw_x);
  const int lane = t & 63, wave = t >> 6;
  const int wr = wave >> 1, wc = wave & 1;
  const int i0 = blockIdx.y * 128, j0 = blockIdx.x * 128;
  const int srow = lane >> 3;
  const int skc = ((lane & 7) ^ srow) * 8;  // swizzled src
  const int fr = lane & 15, fq = lane >> 4;
  const int rsw = fr & 7;
  f32x4 acc[4][4] = {};

  for (int k0 = 0; k0 < 512; k0 += 64) {
#pragma unroll
    for (int s = 0; s < 4; s++) {
      int inst = wave * 4 + s;
      int row = inst * 8 + srow;
      gload_lds16(X + (size_t)(i0 + row) * 512 + k0 + skc, &At[inst * 512]);
      gload_lds16(w + (size_t)(j0 + row) * 512 + k0 + skc, &Bt[inst * 512]);
    }
    __syncthreads();
#pragma unroll
    for (int kk = 0; kk < 64; kk += 32) {
      const int swo = (((kk >> 3) + fq) ^ rsw) << 3;
      bf16x8 af[4], bg[4];
#pragma unroll
      for (int i = 0; i < 4; i++)
        af[i] = *(const bf16x8*)&At[(wr * 64 + i * 16 + fr) * 64 + swo];
#pragma unroll
      for (int j = 0; j < 4; j++)
        bg[j] = *(const bf16x8*)&Bt[(wc * 64 + j * 16 + fr) * 64 + swo];
#pragma unroll
      for (int i = 0; i < 4; i++)
#pragma unroll
        for (int j = 0; j < 4; j++)
          acc[i][j] = __builtin_amdgcn_mfma_f32_16x16x32_bf16(
              af[i], bg[j], acc[i][j], 0, 0, 0);
    }
    __syncthreads();
  }
#pragma unroll
  for (int j = 0; j < 4; j++) {
    int col = j0 + wc * 64 + j * 16 + fr;  // 0..511
    float bia = f ? ((const float*)raw_b)[col]
                  : bf2f(((const unsigned short*)raw_b)[col]);
#pragma unroll
    for (int i = 0; i < 4; i++) {
      int rbase = i0 + wr * 64 + i * 16 + fq * 4;
#pragma unroll
      for (int r = 0; r < 4; r++) {
        out[(size_t)(rbase + r) * 512 + col] = acc[i][j][r] + bia;
      }
    }
  }
}

// ---------------------------------------------------------------------------
extern "C" void kernel_launch(void* const* d_in, const int* in_sizes, int n_in,
                              void* d_out, int out_size, void* d_ws,
                              size_t ws_size, hipStream_t stream) {
  (void)in_sizes; (void)n_in; (void)out_size; (void)ws_size;

  char* w8 = (char*)d_ws;
  unsigned short* cx  = (unsigned short*)(w8 + 0);         // x canon bf16
  unsigned short* cwq = (unsigned short*)(w8 + 16777216);  // qkv_w canon
  unsigned short* cwp = (unsigned short*)(w8 + 18350080);  // proj_w canon
  unsigned short* qkv = (unsigned short*)(w8 + 18876416);  // Q,K,V bf16
  unsigned short* X   = (unsigned short*)(w8 + 69208064);  // attn out bf16
  float* Ql = (float*)(w8 + 85985280);
  float* Kl = (float*)(w8 + 86509568);
  float* k2 = (float*)(w8 + 87033856);
  unsigned short* Ztb = (unsigned short*)(w8 + 88082432);  // Z^T bf16 [bh][d][m]
  unsigned int* gstat = (unsigned int*)(w8 + 88606720);  // [cmax, rmax]
  float* Wp = (float*)(w8 + 88608768);                   // 32*8*4096*4 B
  float* sp = (float*)(w8 + 92803072);                   // 32*8*64*4 B
  unsigned short* Klb = (unsigned short*)(w8 + 92868608); // Kl bf16
  unsigned short* Qlb = (unsigned short*)(w8 + 93130752); // Ql bf16

  conv_all<<<4608, 256, 0, stream>>>(d_in[0], d_in[1], d_in[2], cx, cwq, cwp,
                                     gstat);
  qkv_gemm_mfma<<<dim3(12, 64), 512, 0, stream>>>(cwq, d_in[0], cx, qkv, Ql,
                                                  Kl, Qlb, Klb);
  k3k2_mfma<<<dim3(9, 32), 256, 0, stream>>>(Qlb, qkv, Wp, sp, Ql, Kl, k2,
                                             gstat);
  ns_kernel<<<32, 256, 0, stream>>>(k2, gstat, Wp, sp, Ztb);
  k1x_mfma<<<dim3(32, 32), 256, 0, stream>>>(qkv, Klb, Ztb, X);
  proj_gemm_mfma<<<dim3(4, 128), 256, 0, stream>>>(
      X, cwp, (const unsigned short*)d_in[0], d_in[3], (float*)d_out);
}